// Round 10
// baseline (522.669 us; speedup 1.0000x reference)
//
#include <hip/hip_runtime.h>

typedef unsigned short u16;
typedef unsigned int u32;
typedef short bh8 __attribute__((ext_vector_type(8)));   // 8 bf16 (A/B frag)
typedef float f4 __attribute__((ext_vector_type(4)));    // 4 f32 (C/D frag)
typedef float pf2 __attribute__((ext_vector_type(2)));   // packed f32 pair

__device__ __forceinline__ float bf2f(u16 h) { return __uint_as_float(((u32)h) << 16); }
__device__ __forceinline__ float bflo(u32 u) { return __uint_as_float(u << 16); }
__device__ __forceinline__ float bfhi(u32 u) { return __uint_as_float(u & 0xffff0000u); }
__device__ __forceinline__ u16 f2bf(float f) {
    u32 x = __float_as_uint(f);
    return (u16)((x + 0x7fffu + ((x >> 16) & 1u)) >> 16);  // RNE
}
__device__ __forceinline__ pf2 pkfma(pf2 a, pf2 b, pf2 c) {
    pf2 d;
    asm("v_pk_fma_f32 %0, %1, %2, %3" : "=v"(d) : "v"(a), "v"(b), "v"(c));
    return d;
}
__device__ __forceinline__ pf2 u2f2(u32 u) {
    pf2 r;
    r.x = bflo(u);
    r.y = bfhi(u);
    return r;
}
// 16-lane sum via DPP (VALU pipe, no LDS)
__device__ __forceinline__ float dpp_red16(float x) {
    int y;
    y = __builtin_amdgcn_update_dpp(0, __float_as_int(x), 0xB1, 0xF, 0xF, true);
    x += __int_as_float(y);
    y = __builtin_amdgcn_update_dpp(0, __float_as_int(x), 0x4E, 0xF, 0xF, true);
    x += __int_as_float(y);
    y = __builtin_amdgcn_update_dpp(0, __float_as_int(x), 0x141, 0xF, 0xF, true);
    x += __int_as_float(y);
    y = __builtin_amdgcn_update_dpp(0, __float_as_int(x), 0x140, 0xF, 0xF, true);
    x += __int_as_float(y);
    return x;
}

#define KSCL 0.12751744336457488f  // (1/sqrt(128)) * log2(e)

// ---------------- K0a: A_h = W_node @ Wk_r[h], B_h = W_node @ Wk_s[h] ----------------
__global__ void k0a_kernel(const float* __restrict__ Wn, const float* __restrict__ Wks,
                           const float* __restrict__ Wkr, float* __restrict__ A,
                           float* __restrict__ B) {
    int idx = blockIdx.x * 256 + threadIdx.x;  // 2*4*64*128 = 65536
    if (idx >= 65536) return;
    int which = idx >> 15;
    int rem = idx & 32767;
    int h = rem >> 13;
    int r = rem & 8191;
    int a = r >> 7, dp = r & 127;
    const float* W = which ? Wks : Wkr;
    float acc = 0.f;
    for (int d = 0; d < 128; ++d)
        acc += Wn[a * 128 + d] * W[(h * 128 + d) * 128 + dp];
    (which ? B : A)[(h * 64 + a) * 128 + dp] = acc;
}

// ---------------- K0a2 ---------------------------------------------------------------
__global__ void k0a2_kernel(const float* __restrict__ bn, const float* __restrict__ Wks,
                            const float* __restrict__ Wkr, const float* __restrict__ bks,
                            const float* __restrict__ bkr, float* __restrict__ ybs,
                            float* __restrict__ ybr) {
    int idx = blockIdx.x * 256 + threadIdx.x;  // 2*4*128 = 1024
    if (idx >= 1024) return;
    int which = idx >> 9;
    int rem = idx & 511;
    int h = rem >> 7, dp = rem & 127;
    const float* W = which ? Wks : Wkr;
    const float* b = which ? bks : bkr;
    float acc = b[h * 128 + dp];
    for (int d = 0; d < 128; ++d) acc += bn[d] * W[(h * 128 + d) * 128 + dp];
    (which ? ybs : ybr)[h * 128 + dp] = acc;
}

// ---------------- K0b: assemble Wfold [64 x 708] + biasrow[708] ----------------------
// cols: [0:128) x | [128:640) v(h,i) | [640:704) u k-major: 640+k*4+h | [704:708) c0_h
__global__ void k0b_kernel(const float* __restrict__ Wn, const float* __restrict__ bn,
                           const float* __restrict__ A, const float* __restrict__ B,
                           const float* __restrict__ ybr, const float* __restrict__ ybs,
                           const float* __restrict__ Wks, const float* __restrict__ Wedge,
                           const float* __restrict__ bks, const float* __restrict__ bedge,
                           float* __restrict__ Wfold, float* __restrict__ biasrow) {
    int idx = blockIdx.x * 256 + threadIdx.x;  // 65*708
    if (idx >= 65 * 708) return;
    int a = idx / 708, c = idx % 708;
    float val;
    if (c < 128) {
        val = (a < 64) ? Wn[a * 128 + c] : bn[c];
    } else if (c < 640) {
        int h = (c - 128) >> 7, i = (c - 128) & 127;
        const float* rv = (a < 64) ? &A[(h * 64 + a) * 128] : &ybr[h * 128];
        float s = 0.f;
        for (int d = 0; d < 128; ++d) s += rv[d] * Wks[(h * 128 + i) * 128 + d];
        val = s;
    } else if (c < 704) {
        int k = (c - 640) >> 2, h = (c - 640) & 3;
        const float* rv = (a < 64) ? &B[(h * 64 + a) * 128] : &ybs[h * 128];
        float s = 0.f;
        for (int d = 0; d < 128; ++d) s += rv[d] * Wedge[k * 128 + d];
        val = s;
    } else {
        int h = c - 704;
        const float* rv = (a < 64) ? &B[(h * 64 + a) * 128] : &ybs[h * 128];
        float s = 0.f;
        for (int d = 0; d < 128; ++d) s += rv[d] * bedge[d];
        val = s;
    }
    if (a < 64) Wfold[(size_t)a * 708 + c] = val;
    else biasrow[c] = val;
}

// ---------------- wconv: bf16 transposed copies of Wfold and W_out -------------------
__global__ void wconv_kernel(const float* __restrict__ Wfold, const float* __restrict__ Wout,
                             u16* __restrict__ WfT, u16* __restrict__ WoT) {
    int i = blockIdx.x * 256 + threadIdx.x;
    if (i < 768 * 64) {
        int c = i >> 6, k = i & 63;
        WfT[i] = f2bf(c < 708 ? Wfold[(size_t)k * 708 + c] : 0.f);
    }
    int j = i - 768 * 64;
    if (j >= 0 && j < 128 * 512) {
        int c = j >> 9, k = j & 511;
        WoT[j] = f2bf(Wout[(size_t)k * 128 + c]);
    }
}

// ---------------- G1 (MFMA): split tables Xc[N,128], V[N,512](pre-scaled), U[N,64],
//                  E0[N,4] = exp2(kscl*c0) ------------------------------------------
__global__ __launch_bounds__(256) void g1_kernel(const float* __restrict__ nodes,
                                                 const u16* __restrict__ WfT,
                                                 const float* __restrict__ biasrow,
                                                 u16* __restrict__ Xc, u16* __restrict__ V,
                                                 u16* __restrict__ U, float* __restrict__ E0,
                                                 int N) {
    __shared__ u16 Asm[64][72];
    __shared__ u16 Bsm[128][72];
    int t = threadIdx.x;
    int r0 = blockIdx.x * 64, c0 = blockIdx.y * 128;
    {
        int row = t >> 2, cb = (t & 3) * 16;
        int r = r0 + row;
        u16 pk[16];
        if (r < N) {
            const float* src = &nodes[(size_t)r * 64 + cb];
#pragma unroll
            for (int q = 0; q < 16; ++q) pk[q] = f2bf(src[q]);
        } else {
#pragma unroll
            for (int q = 0; q < 16; ++q) pk[q] = 0;
        }
        *(uint4*)&Asm[row][cb] = *(const uint4*)&pk[0];
        *(uint4*)&Asm[row][cb + 8] = *(const uint4*)&pk[8];
    }
    {
        int col = t >> 1, ks = (t & 1) * 32;
        const u16* src = &WfT[(size_t)(c0 + col) * 64 + ks];
        uint4 v0 = *(const uint4*)src;
        uint4 v1 = *(const uint4*)(src + 8);
        uint4 v2 = *(const uint4*)(src + 16);
        uint4 v3 = *(const uint4*)(src + 24);
        *(uint4*)&Bsm[col][ks] = v0;
        *(uint4*)&Bsm[col][ks + 8] = v1;
        *(uint4*)&Bsm[col][ks + 16] = v2;
        *(uint4*)&Bsm[col][ks + 24] = v3;
    }
    __syncthreads();
    int lane = t & 63, wave = t >> 6;
    int wm = wave >> 1, wn = wave & 1;
    int lr = lane & 15, lk = lane >> 4;
    f4 acc[2][4] = {};
#pragma unroll
    for (int kk = 0; kk < 2; ++kk) {
        bh8 a[2], b[4];
#pragma unroll
        for (int am = 0; am < 2; ++am)
            a[am] = *(const bh8*)&Asm[wm * 32 + am * 16 + lr][kk * 32 + lk * 8];
#pragma unroll
        for (int bn = 0; bn < 4; ++bn)
            b[bn] = *(const bh8*)&Bsm[wn * 64 + bn * 16 + lr][kk * 32 + lk * 8];
#pragma unroll
        for (int am = 0; am < 2; ++am)
#pragma unroll
            for (int bn = 0; bn < 4; ++bn)
                acc[am][bn] = __builtin_amdgcn_mfma_f32_16x16x32_bf16(a[am], b[bn], acc[am][bn], 0, 0, 0);
    }
#pragma unroll
    for (int am = 0; am < 2; ++am)
#pragma unroll
        for (int bn = 0; bn < 4; ++bn) {
            int c = c0 + wn * 64 + bn * 16 + lr;
            if (c < 708) {
                float brow = biasrow[c];
#pragma unroll
                for (int q = 0; q < 4; ++q) {
                    int r = r0 + wm * 32 + am * 16 + lk * 4 + q;
                    if (r < N) {
                        float val = acc[am][bn][q] + brow;
                        if (c < 128) Xc[(size_t)r * 128 + c] = f2bf(val);
                        else if (c < 640) V[(size_t)r * 512 + (c - 128)] = f2bf(val * KSCL);
                        else if (c < 704) U[(size_t)r * 64 + (c - 640)] = f2bf(val * KSCL);
                        else E0[(size_t)r * 4 + (c - 704)] = exp2f(val * KSCL);
                    }
                }
            }
        }
}

// ---------------- CSR build ----------------------------------------------------------
__global__ void hist_kernel(const int* __restrict__ recv, int* __restrict__ deg, int E) {
    int e = blockIdx.x * 256 + threadIdx.x;
    if (e < E) atomicAdd(&deg[recv[e]], 1);
}

__global__ __launch_bounds__(1024) void scan1_kernel(const int* __restrict__ deg,
                                                     int* __restrict__ pre,
                                                     int* __restrict__ bsum, int N) {
    __shared__ int sm[1024];
    int b = blockIdx.x, t = threadIdx.x;
    int i = b * 1024 + t;
    int v = (i < N) ? deg[i] : 0;
    sm[t] = v;
    __syncthreads();
    for (int off = 1; off < 1024; off <<= 1) {
        int u = (t >= off) ? sm[t - off] : 0;
        __syncthreads();
        sm[t] += u;
        __syncthreads();
    }
    if (i < N) pre[i] = sm[t] - v;
    if (t == 1023) bsum[b] = sm[1023];
}

__global__ void scan2_kernel(int* __restrict__ bsum, int* __restrict__ boff, int nb) {
    int t = threadIdx.x;  // 64 threads, nb <= 64
    int own = (t < nb) ? bsum[t] : 0;
    int v = own;
#pragma unroll
    for (int off = 1; off < 64; off <<= 1) {
        int u = __shfl_up(v, off);
        if (t >= off) v += u;
    }
    if (t < nb) boff[t] = v - own;
    if (t == 63) boff[64] = v;
}

__global__ void scan3_kernel(const int* __restrict__ pre, const int* __restrict__ boff,
                             int* __restrict__ row_start, int* __restrict__ cursor, int N) {
    int i = blockIdx.x * 1024 + threadIdx.x;
    if (i < N) {
        int rsv = pre[i] + boff[i >> 10];
        row_start[i] = rsv;
        cursor[i] = rsv;
    }
    if (i == N) row_start[N] = boff[64];
}

// scatter writes fused (edge, sender) pairs -> en reads both with ONE load
__global__ void scatter_kernel(const int* __restrict__ recv, const int* __restrict__ senders,
                               int* __restrict__ cursor, int2* __restrict__ esp, int E) {
    int e = blockIdx.x * 256 + threadIdx.x;
    if (e < E) {
        int s = senders[e];
        int p = atomicAdd(&cursor[recv[e]], 1);
        esp[p] = make_int2(e, s);
    }
}

// ---------------- EN v8: rotated node pipeline — next node's prologue overlaps -------
// Wave = node. Lane = (g,k16). 8-edge steps, 2 COMPs/step. Next node's rs/V/idx/payload
// are issued during the current node's body/epilogue.
__global__ __launch_bounds__(256, 4) void en_kernel(const int* __restrict__ row_start,
                                                    const int2* __restrict__ esp,
                                                    const float* __restrict__ edges,
                                                    const u16* __restrict__ Xc,
                                                    const u16* __restrict__ V,
                                                    const u16* __restrict__ Uu,
                                                    const float* __restrict__ E0,
                                                    const float* __restrict__ W_edge,
                                                    const float* __restrict__ b_edge,
                                                    u16* __restrict__ agg, int N) {
    __shared__ float Wl[2048];  // swizzled: (k, ch=8*k16+2i+b) at k*128+32*i+2*k16+b
    int t = threadIdx.x;
    for (int i = t; i < 2048; i += 256) {
        int k = i >> 7, ch = i & 127;
        int pos = (k << 7) | ((((ch >> 1) & 3) << 5) | (((ch >> 3) & 15) << 1) | (ch & 1));
        Wl[pos] = W_edge[i];
    }
    __syncthreads();
    int lane = t & 63, wid = t >> 6;
    int g = lane >> 4, k16 = lane & 15;
    int nw = blockIdx.x * 4 + wid;
    int NW = gridDim.x * 4;

#define LOADP(Xq, Uq, Eq, Zq, eI, sI)                                       \
    {                                                                       \
        Xq = *(const uint4*)(Xc + (size_t)(sI)*128 + 8 * k16);              \
        Uq = *(const uint2*)(Uu + (size_t)(sI)*64 + k16 * 4);               \
        Eq = edges[(size_t)(eI)*16 + k16];                                  \
        Zq = *(const float4*)(E0 + (size_t)(sI)*4);                         \
    }

#define COMP(Xq, Uq, Eq, Zq, act)                                           \
    {                                                                       \
        pf2 X0 = u2f2(Xq.x), X1 = u2f2(Xq.y), X2 = u2f2(Xq.z), X3 = u2f2(Xq.w); \
        float uh[4] = {bflo(Uq.x), bfhi(Uq.x), bflo(Uq.y), bfhi(Uq.y)};     \
        float e0a[4] = {Zq.x, Zq.y, Zq.z, Zq.w};                            \
        _Pragma("unroll") for (int h = 0; h < 4; ++h) {                     \
            pf2 p2 = {Eq * uh[h], 0.f};                                     \
            p2 = pkfma(X0, vr[h][0], p2); p2 = pkfma(X1, vr[h][1], p2);     \
            p2 = pkfma(X2, vr[h][2], p2); p2 = pkfma(X3, vr[h][3], p2);     \
            float p = dpp_red16(p2.x + p2.y);                               \
            float wh = (act) ? e0a[h] * exp2f(p) : 0.f;                     \
            Ss[h] += wh; aE[h] = fmaf(wh, Eq, aE[h]);                       \
            pf2 w2 = {wh, wh};                                              \
            aX[h][0] = pkfma(w2, X0, aX[h][0]);                             \
            aX[h][1] = pkfma(w2, X1, aX[h][1]);                             \
            aX[h][2] = pkfma(w2, X2, aX[h][2]);                             \
            aX[h][3] = pkfma(w2, X3, aX[h][3]);                             \
        }                                                                   \
    }

    int n = nw;
    if (n >= N) return;
    int rs = row_start[n], re = row_start[n + 1];
    // packed V-row for current node (prefetched across iterations)
    uint4 vn0, vn1, vn2, vn3;
    {
        const u16* Vr = V + (size_t)n * 512;
        vn0 = *(const uint4*)(Vr + 0 * 128 + 8 * k16);
        vn1 = *(const uint4*)(Vr + 1 * 128 + 8 * k16);
        vn2 = *(const uint4*)(Vr + 2 * 128 + 8 * k16);
        vn3 = *(const uint4*)(Vr + 3 * 128 + 8 * k16);
    }
    // first node: idx for steps 0,1 + payload for step 0 slots
    int eB0, sB0, eB1, sB1;  // step (s+1) indices during loop
    uint4 xP0, xP1;
    uint2 uP0, uP1;
    float eP0, eP1;
    float4 zP0, zP1;
    {
        int deg = re - rs;
        int2 pvA = {0, 0}, pvB = {0, 0};
        if (lane < 8 && deg > 0) {
            int jj = lane;
            if (jj >= deg) jj = deg - 1;
            pvA = esp[rs + jj];
            int jj2 = 8 + lane;
            if (jj2 >= deg) jj2 = deg - 1;
            pvB = esp[rs + jj2];
        }
        int eA0 = __shfl(pvA.x, g), sA0 = __shfl(pvA.y, g);
        int eA1 = __shfl(pvA.x, 4 + g), sA1 = __shfl(pvA.y, 4 + g);
        eB0 = __shfl(pvB.x, g); sB0 = __shfl(pvB.y, g);
        eB1 = __shfl(pvB.x, 4 + g); sB1 = __shfl(pvB.y, 4 + g);
        LOADP(xP0, uP0, eP0, zP0, eA0, sA0);
        LOADP(xP1, uP1, eP1, zP1, eA1, sA1);
    }

    while (true) {
        int deg = re - rs;
        int n2 = n + NW;
        bool more = (n2 < N);
        int rs2 = 0, re2 = 0;
        if (more) {  // prefetch next node's CSR bounds early
            rs2 = row_start[n2];
            re2 = row_start[n2 + 1];
        }
        // unpack vr (vn regs die here), then issue next node's V-row into them
        pf2 vr[4][4];
        vr[0][0] = u2f2(vn0.x); vr[0][1] = u2f2(vn0.y); vr[0][2] = u2f2(vn0.z); vr[0][3] = u2f2(vn0.w);
        vr[1][0] = u2f2(vn1.x); vr[1][1] = u2f2(vn1.y); vr[1][2] = u2f2(vn1.z); vr[1][3] = u2f2(vn1.w);
        vr[2][0] = u2f2(vn2.x); vr[2][1] = u2f2(vn2.y); vr[2][2] = u2f2(vn2.z); vr[2][3] = u2f2(vn2.w);
        vr[3][0] = u2f2(vn3.x); vr[3][1] = u2f2(vn3.y); vr[3][2] = u2f2(vn3.z); vr[3][3] = u2f2(vn3.w);
        {
            const u16* Vr = V + (size_t)(more ? n2 : n) * 512;
            vn0 = *(const uint4*)(Vr + 0 * 128 + 8 * k16);
            vn1 = *(const uint4*)(Vr + 1 * 128 + 8 * k16);
            vn2 = *(const uint4*)(Vr + 2 * 128 + 8 * k16);
            vn3 = *(const uint4*)(Vr + 3 * 128 + 8 * k16);
        }
        pf2 aX[4][4] = {};
        float Ss[4] = {0.f, 0.f, 0.f, 0.f};
        float aE[4] = {0.f, 0.f, 0.f, 0.f};

        if (deg > 0) {
            int nst = (deg + 7) >> 3;
            for (int s = 0; s < nst; ++s) {
                uint4 xc0 = xP0, xc1 = xP1;
                uint2 uc0 = uP0, uc1 = uP1;
                float ec0 = eP0, ec1 = eP1;
                float4 zc0 = zP0, zc1 = zP1;
                int base = s * 8;
                if (s + 1 < nst) {  // prefetch next step's payload
                    LOADP(xP0, uP0, eP0, zP0, eB0, sB0);
                    LOADP(xP1, uP1, eP1, zP1, eB1, sB1);
                    if (s + 2 < nst) {  // prefetch step-after-next's indices
                        int2 pv = {0, 0};
                        if (lane < 8) {
                            int jj = (s + 2) * 8 + lane;
                            if (jj >= deg) jj = deg - 1;
                            pv = esp[rs + jj];
                        }
                        eB0 = __shfl(pv.x, g); sB0 = __shfl(pv.y, g);
                        eB1 = __shfl(pv.x, 4 + g); sB1 = __shfl(pv.y, 4 + g);
                    }
                }
                COMP(xc0, uc0, ec0, zc0, base + g < deg);
                COMP(xc1, uc1, ec1, zc1, base + 4 + g < deg);
            }
        }
        // tail: issue next node's raw idx loads; epilogue covers their latency
        int2 pvA = {0, 0}, pvB = {0, 0};
        if (more) {
            int deg2 = re2 - rs2;
            if (lane < 8 && deg2 > 0) {
                int jj = lane;
                if (jj >= deg2) jj = deg2 - 1;
                pvA = esp[rs2 + jj];
                int jj2 = 8 + lane;
                if (jj2 >= deg2) jj2 = deg2 - 1;
                pvB = esp[rs2 + jj2];
            }
        }
        // epilogue: cross-group reduce (sum over the 4 edge-groups)
#pragma unroll
        for (int h = 0; h < 4; ++h) {
#pragma unroll
            for (int i = 0; i < 4; ++i) {
                pf2 v = aX[h][i];
                v.x += __shfl_xor(v.x, 16); v.y += __shfl_xor(v.y, 16);
                v.x += __shfl_xor(v.x, 32); v.y += __shfl_xor(v.y, 32);
                aX[h][i] = v;
            }
            Ss[h] += __shfl_xor(Ss[h], 16); Ss[h] += __shfl_xor(Ss[h], 32);
            aE[h] += __shfl_xor(aE[h], 16); aE[h] += __shfl_xor(aE[h], 32);
        }
        // finalize: group g owns head g over the full k range
        pf2 axg[4];
#pragma unroll
        for (int i = 0; i < 4; ++i)
            axg[i] = g == 0 ? aX[0][i] : g == 1 ? aX[1][i] : g == 2 ? aX[2][i] : aX[3][i];
        float aEg = g == 0 ? aE[0] : g == 1 ? aE[1] : g == 2 ? aE[2] : aE[3];
        float Sg = g == 0 ? Ss[0] : g == 1 ? Ss[1] : g == 2 ? Ss[2] : Ss[3];
        const pf2* Wp = (const pf2*)Wl;
#pragma unroll
        for (int kk = 0; kk < 16; ++kk) {
            float a = __shfl(aEg, (g << 4) | kk);  // broadcast within own group
            pf2 a2 = {a, a};
            int base = (kk << 6) + k16;  // same addr across groups -> LDS broadcast
            axg[0] = pkfma(a2, Wp[base], axg[0]);
            axg[1] = pkfma(a2, Wp[base + 16], axg[1]);
            axg[2] = pkfma(a2, Wp[base + 32], axg[2]);
            axg[3] = pkfma(a2, Wp[base + 48], axg[3]);
        }
        {
            float inv = (deg > 0 && Sg > 0.f) ? 1.f / Sg : 0.f;
            float bes = (deg > 0) ? 1.f : 0.f;
            const float* br = &b_edge[8 * k16];
            u32 o0 = (u32)f2bf(axg[0].x * inv + bes * br[0]) |
                     ((u32)f2bf(axg[0].y * inv + bes * br[1]) << 16);
            u32 o1 = (u32)f2bf(axg[1].x * inv + bes * br[2]) |
                     ((u32)f2bf(axg[1].y * inv + bes * br[3]) << 16);
            u32 o2 = (u32)f2bf(axg[2].x * inv + bes * br[4]) |
                     ((u32)f2bf(axg[2].y * inv + bes * br[5]) << 16);
            u32 o3 = (u32)f2bf(axg[3].x * inv + bes * br[6]) |
                     ((u32)f2bf(axg[3].y * inv + bes * br[7]) << 16);
            uint4 st = {o0, o1, o2, o3};
            *(uint4*)(agg + (size_t)n * 512 + g * 128 + 8 * k16) = st;
        }
        if (!more) break;
        // distribute next node's idx (pv loads have had the epilogue to land),
        // then issue its step-0 payload so it is in flight when the loop rotates.
        {
            int eA0 = __shfl(pvA.x, g), sA0 = __shfl(pvA.y, g);
            int eA1 = __shfl(pvA.x, 4 + g), sA1 = __shfl(pvA.y, 4 + g);
            eB0 = __shfl(pvB.x, g); sB0 = __shfl(pvB.y, g);
            eB1 = __shfl(pvB.x, 4 + g); sB1 = __shfl(pvB.y, 4 + g);
            LOADP(xP0, uP0, eP0, zP0, eA0, sA0);
            LOADP(xP1, uP1, eP1, zP1, eA1, sA1);
        }
        n = n2; rs = rs2; re = re2;
    }
#undef LOADP
#undef COMP
}

// ---------------- G3 (MFMA): out = relu(x + agg @ W_out + b_out) ---------------------
__global__ __launch_bounds__(256) void g3_kernel(const u16* __restrict__ Xc,
                                                 const u16* __restrict__ agg,
                                                 const u16* __restrict__ WoT,
                                                 const float* __restrict__ bout,
                                                 const int* __restrict__ avgflag,
                                                 float* __restrict__ out, int N) {
    int t = threadIdx.x;
    int r0 = blockIdx.x * 64;
    if (*avgflag) {
        for (int i = t; i < 64 * 128; i += 256) {
            int n = r0 + (i >> 7), j = i & 127;
            if (n < N) {
                float s = 0.f;
#pragma unroll
                for (int h = 0; h < 4; ++h) s += bf2f(agg[(size_t)n * 512 + h * 128 + j]);
                float v = bf2f(Xc[(size_t)n * 128 + j]) + 0.25f * s;
                out[(size_t)n * 128 + j] = v > 0.f ? v : 0.f;
            }
        }
        return;
    }
    __shared__ u16 Asm[64][72];
    __shared__ u16 Bsm[128][72];
    int lane = t & 63, wave = t >> 6;
    int wm = wave >> 1, wn = wave & 1;
    int lr = lane & 15, lk = lane >> 4;
    f4 acc[2][4] = {};
    for (int kb = 0; kb < 8; ++kb) {
        if (kb) __syncthreads();
        {
            int row = t >> 2, ks = (t & 3) * 16;
            int r = r0 + row;
            uint4 v0 = {0, 0, 0, 0}, v1 = {0, 0, 0, 0};
            if (r < N) {
                const u16* src = &agg[(size_t)r * 512 + kb * 64 + ks];
                v0 = *(const uint4*)src;
                v1 = *(const uint4*)(src + 8);
            }
            *(uint4*)&Asm[row][ks] = v0;
            *(uint4*)&Asm[row][ks + 8] = v1;
        }
        {
            int col = t >> 1, ks = (t & 1) * 32;
            const u16* src = &WoT[(size_t)col * 512 + kb * 64 + ks];
            uint4 v0 = *(const uint4*)src;
            uint4 v1 = *(const uint4*)(src + 8);
            uint4 v2 = *(const uint4*)(src + 16);
            uint4 v3 = *(const uint4*)(src + 24);
            *(uint4*)&Bsm[col][ks] = v0;
            *(uint4*)&Bsm[col][ks + 8] = v1;
            *(uint4*)&Bsm[col][ks + 16] = v2;
            *(uint4*)&Bsm[col][ks + 24] = v3;
        }
        __syncthreads();
#pragma unroll
        for (int kk = 0; kk < 2; ++kk) {
            bh8 a[2], b[4];
#pragma unroll
            for (int am = 0; am < 2; ++am)
                a[am] = *(const bh8*)&Asm[wm * 32 + am * 16 + lr][kk * 32 + lk * 8];
#pragma unroll
            for (int bn = 0; bn < 4; ++bn)
                b[bn] = *(const bh8*)&Bsm[wn * 64 + bn * 16 + lr][kk * 32 + lk * 8];
#pragma unroll
            for (int am = 0; am < 2; ++am)
#pragma unroll
                for (int bn = 0; bn < 4; ++bn)
                    acc[am][bn] = __builtin_amdgcn_mfma_f32_16x16x32_bf16(a[am], b[bn], acc[am][bn], 0, 0, 0);
        }
    }
#pragma unroll
    for (int am = 0; am < 2; ++am)
#pragma unroll
        for (int bn = 0; bn < 4; ++bn) {
            int c = wn * 64 + bn * 16 + lr;
            float bc = bout[c];
#pragma unroll
            for (int q = 0; q < 4; ++q) {
                int r = r0 + wm * 32 + am * 16 + lk * 4 + q;
                if (r < N) {
                    float v = acc[am][bn][q] + bc + bf2f(Xc[(size_t)r * 128 + c]);
                    out[(size_t)r * 128 + c] = v > 0.f ? v : 0.f;
                }
            }
        }
}

// ---------------- launch --------------------------------------------------------------
extern "C" void kernel_launch(void* const* d_in, const int* in_sizes, int n_in, void* d_out,
                              int out_size, void* d_ws, size_t ws_size, hipStream_t stream) {
    const float* nodes = (const float*)d_in[0];
    const float* edges = (const float*)d_in[1];
    const int* senders = (const int*)d_in[2];
    const int* receivers = (const int*)d_in[3];
    const int* avgflag = (const int*)d_in[4];
    const float* W_node = (const float*)d_in[5];
    const float* b_node = (const float*)d_in[6];
    const float* W_edge = (const float*)d_in[7];
    const float* b_edge = (const float*)d_in[8];
    const float* Wk_s = (const float*)d_in[9];
    const float* bk_s = (const float*)d_in[10];
    const float* Wk_r = (const float*)d_in[11];
    const float* bk_r = (const float*)d_in[12];
    const float* W_out = (const float*)d_in[13];
    const float* b_out = (const float*)d_in[14];
    int N = in_sizes[0] / 64;
    int E = in_sizes[2];
    float* outp = (float*)d_out;

    char* base = (char*)d_ws;
    size_t off = 0;
    auto alloc = [&](size_t nbytes) -> char* {
        char* p = base + off;
        off = (off + nbytes + 255) & ~(size_t)255;
        return p;
    };
    u16* Xc = (u16*)alloc((size_t)N * 128 * 2);
    u16* V = (u16*)alloc((size_t)N * 512 * 2);
    u16* U = (u16*)alloc((size_t)N * 64 * 2);
    float* E0 = (float*)alloc((size_t)N * 4 * 4);
    u16* agg = (u16*)alloc((size_t)N * 512 * 2);
    int* deg = (int*)alloc((size_t)N * 4);
    int* row_start = (int*)alloc((size_t)(N + 1) * 4);
    int* cursor = (int*)alloc((size_t)N * 4);
    int2* esp = (int2*)alloc((size_t)E * 8);
    int* pre = (int*)alloc((size_t)N * 4);
    int* bsum = (int*)alloc((size_t)128 * 4);
    int* boff = (int*)alloc((size_t)128 * 4);
    float* A = (float*)alloc((size_t)4 * 64 * 128 * 4);
    float* B = (float*)alloc((size_t)4 * 64 * 128 * 4);
    float* ybr = (float*)alloc((size_t)4 * 128 * 4);
    float* ybs = (float*)alloc((size_t)4 * 128 * 4);
    float* Wfold = (float*)alloc((size_t)64 * 708 * 4);
    float* biasrow = (float*)alloc((size_t)712 * 4);
    u16* WfT = (u16*)alloc((size_t)768 * 64 * 2);
    u16* WoT = (u16*)alloc((size_t)128 * 512 * 2);

    int nb = (N + 1023) >> 10;

    hipMemsetAsync(deg, 0, (size_t)N * 4, stream);
    k0a_kernel<<<256, 256, 0, stream>>>(W_node, Wk_s, Wk_r, A, B);
    k0a2_kernel<<<4, 256, 0, stream>>>(b_node, Wk_s, Wk_r, bk_s, bk_r, ybs, ybr);
    k0b_kernel<<<(65 * 708 + 255) / 256, 256, 0, stream>>>(W_node, b_node, A, B, ybr, ybs,
                                                           Wk_s, W_edge, bk_s, b_edge, Wfold,
                                                           biasrow);
    wconv_kernel<<<(768 * 64 + 128 * 512 + 255) / 256, 256, 0, stream>>>(Wfold, W_out, WfT, WoT);
    dim3 g1grid((N + 63) / 64, 6);
    g1_kernel<<<g1grid, 256, 0, stream>>>(nodes, WfT, biasrow, Xc, V, U, E0, N);
    hist_kernel<<<(E + 255) / 256, 256, 0, stream>>>(receivers, deg, E);
    scan1_kernel<<<nb, 1024, 0, stream>>>(deg, pre, bsum, N);
    scan2_kernel<<<1, 64, 0, stream>>>(bsum, boff, nb);
    scan3_kernel<<<(N + 1024) / 1024, 1024, 0, stream>>>(pre, boff, row_start, cursor, N);
    scatter_kernel<<<(E + 255) / 256, 256, 0, stream>>>(receivers, senders, cursor, esp, E);
    en_kernel<<<4096, 256, 0, stream>>>(row_start, esp, edges, Xc, V, U, E0, W_edge,
                                        b_edge, agg, N);
    g3_kernel<<<(N + 63) / 64, 256, 0, stream>>>(Xc, agg, WoT, b_out, avgflag, outp, N);
}

// Round 11
// 325.831 us; speedup vs baseline: 1.6041x; 1.6041x over previous
//
#include <hip/hip_runtime.h>

typedef unsigned short u16;
typedef unsigned int u32;
typedef short bh8 __attribute__((ext_vector_type(8)));   // 8 bf16 (A/B frag)
typedef float f4 __attribute__((ext_vector_type(4)));    // 4 f32 (C/D frag)
typedef float pf2 __attribute__((ext_vector_type(2)));   // packed f32 pair

__device__ __forceinline__ float bf2f(u16 h) { return __uint_as_float(((u32)h) << 16); }
__device__ __forceinline__ float bflo(u32 u) { return __uint_as_float(u << 16); }
__device__ __forceinline__ float bfhi(u32 u) { return __uint_as_float(u & 0xffff0000u); }
__device__ __forceinline__ u16 f2bf(float f) {
    u32 x = __float_as_uint(f);
    return (u16)((x + 0x7fffu + ((x >> 16) & 1u)) >> 16);  // RNE
}
__device__ __forceinline__ pf2 pkfma(pf2 a, pf2 b, pf2 c) {
    pf2 d;
    asm("v_pk_fma_f32 %0, %1, %2, %3" : "=v"(d) : "v"(a), "v"(b), "v"(c));
    return d;
}
__device__ __forceinline__ pf2 u2f2(u32 u) {
    pf2 r;
    r.x = bflo(u);
    r.y = bfhi(u);
    return r;
}
// 16-lane sum via DPP (VALU pipe, no LDS)
__device__ __forceinline__ float dpp_red16(float x) {
    int y;
    y = __builtin_amdgcn_update_dpp(0, __float_as_int(x), 0xB1, 0xF, 0xF, true);
    x += __int_as_float(y);
    y = __builtin_amdgcn_update_dpp(0, __float_as_int(x), 0x4E, 0xF, 0xF, true);
    x += __int_as_float(y);
    y = __builtin_amdgcn_update_dpp(0, __float_as_int(x), 0x141, 0xF, 0xF, true);
    x += __int_as_float(y);
    y = __builtin_amdgcn_update_dpp(0, __float_as_int(x), 0x140, 0xF, 0xF, true);
    x += __int_as_float(y);
    return x;
}

#define KSCL 0.12751744336457488f  // (1/sqrt(128)) * log2(e)

// ---------------- K0a: A_h = W_node@Wk_r[h], B_h = W_node@Wk_s[h], WoT, yb vectors ---
// idx < 65536: A/B.  [65536,131072): WoT transpose.  [131072,132096): ybs/ybr.
__global__ void k0a_kernel(const float* __restrict__ Wn, const float* __restrict__ Wks,
                           const float* __restrict__ Wkr, const float* __restrict__ Wout,
                           const float* __restrict__ bn, const float* __restrict__ bks,
                           const float* __restrict__ bkr, float* __restrict__ A,
                           float* __restrict__ B, u16* __restrict__ WoT,
                           float* __restrict__ ybs, float* __restrict__ ybr) {
    int idx = blockIdx.x * 256 + threadIdx.x;
    if (idx < 65536) {
        int which = idx >> 15;
        int rem = idx & 32767;
        int h = rem >> 13;
        int r = rem & 8191;
        int a = r >> 7, dp = r & 127;
        const float* W = which ? Wks : Wkr;
        float acc = 0.f;
        for (int d = 0; d < 128; ++d)
            acc += Wn[a * 128 + d] * W[(h * 128 + d) * 128 + dp];
        (which ? B : A)[(h * 64 + a) * 128 + dp] = acc;
    } else if (idx < 131072) {
        int j = idx - 65536;
        int c = j >> 9, k = j & 511;
        WoT[j] = f2bf(Wout[(size_t)k * 128 + c]);
    } else if (idx < 132096) {
        int j = idx - 131072;
        int which = j >> 9;
        int rem = j & 511;
        int h = rem >> 7, dp = rem & 127;
        const float* W = which ? Wks : Wkr;
        const float* b = which ? bks : bkr;
        float acc = b[h * 128 + dp];
        for (int d = 0; d < 128; ++d) acc += bn[d] * W[(h * 128 + d) * 128 + dp];
        (which ? ybs : ybr)[h * 128 + dp] = acc;
    }
}

// ---------------- K0b: assemble WfT [768 x 64] (bf16, transposed) + biasrow[708] -----
// col c: [0:128) x | [128:640) v(h,i) | [640:704) u k-major | [704:708) c0_h | [708:768)=0
__global__ void k0b_kernel(const float* __restrict__ Wn, const float* __restrict__ bn,
                           const float* __restrict__ A, const float* __restrict__ B,
                           const float* __restrict__ ybr, const float* __restrict__ ybs,
                           const float* __restrict__ Wks, const float* __restrict__ Wedge,
                           const float* __restrict__ bks, const float* __restrict__ bedge,
                           u16* __restrict__ WfT, float* __restrict__ biasrow) {
    int idx = blockIdx.x * 256 + threadIdx.x;  // 65*708 + 60*64 (zero tail)
    if (idx >= 65 * 708 + 60 * 64) return;
    if (idx >= 65 * 708) {
        int j = idx - 65 * 708;
        WfT[(708 + (j >> 6)) * 64 + (j & 63)] = 0;
        return;
    }
    int a = idx / 708, c = idx % 708;
    float val;
    if (c < 128) {
        val = (a < 64) ? Wn[a * 128 + c] : bn[c];
    } else if (c < 640) {
        int h = (c - 128) >> 7, i = (c - 128) & 127;
        const float* rv = (a < 64) ? &A[(h * 64 + a) * 128] : &ybr[h * 128];
        float s = 0.f;
        for (int d = 0; d < 128; ++d) s += rv[d] * Wks[(h * 128 + i) * 128 + d];
        val = s;
    } else if (c < 704) {
        int k = (c - 640) >> 2, h = (c - 640) & 3;
        const float* rv = (a < 64) ? &B[(h * 64 + a) * 128] : &ybs[h * 128];
        float s = 0.f;
        for (int d = 0; d < 128; ++d) s += rv[d] * Wedge[k * 128 + d];
        val = s;
    } else {
        int h = c - 704;
        const float* rv = (a < 64) ? &B[(h * 64 + a) * 128] : &ybs[h * 128];
        float s = 0.f;
        for (int d = 0; d < 128; ++d) s += rv[d] * bedge[d];
        val = s;
    }
    if (a < 64) WfT[(size_t)c * 64 + a] = f2bf(val);
    else biasrow[c] = val;
}

// ---------------- G1 (MFMA): split tables Xc[N,128], V[N,512](pre-scaled), U[N,64],
//                  E0[N,4] = exp2(kscl*c0) ------------------------------------------
__global__ __launch_bounds__(256) void g1_kernel(const float* __restrict__ nodes,
                                                 const u16* __restrict__ WfT,
                                                 const float* __restrict__ biasrow,
                                                 u16* __restrict__ Xc, u16* __restrict__ V,
                                                 u16* __restrict__ U, float* __restrict__ E0,
                                                 int N) {
    __shared__ u16 Asm[64][72];
    __shared__ u16 Bsm[128][72];
    int t = threadIdx.x;
    int r0 = blockIdx.x * 64, c0 = blockIdx.y * 128;
    {
        int row = t >> 2, cb = (t & 3) * 16;
        int r = r0 + row;
        u16 pk[16];
        if (r < N) {
            const float* src = &nodes[(size_t)r * 64 + cb];
#pragma unroll
            for (int q = 0; q < 16; ++q) pk[q] = f2bf(src[q]);
        } else {
#pragma unroll
            for (int q = 0; q < 16; ++q) pk[q] = 0;
        }
        *(uint4*)&Asm[row][cb] = *(const uint4*)&pk[0];
        *(uint4*)&Asm[row][cb + 8] = *(const uint4*)&pk[8];
    }
    {
        int col = t >> 1, ks = (t & 1) * 32;
        const u16* src = &WfT[(size_t)(c0 + col) * 64 + ks];
        uint4 v0 = *(const uint4*)src;
        uint4 v1 = *(const uint4*)(src + 8);
        uint4 v2 = *(const uint4*)(src + 16);
        uint4 v3 = *(const uint4*)(src + 24);
        *(uint4*)&Bsm[col][ks] = v0;
        *(uint4*)&Bsm[col][ks + 8] = v1;
        *(uint4*)&Bsm[col][ks + 16] = v2;
        *(uint4*)&Bsm[col][ks + 24] = v3;
    }
    __syncthreads();
    int lane = t & 63, wave = t >> 6;
    int wm = wave >> 1, wn = wave & 1;
    int lr = lane & 15, lk = lane >> 4;
    f4 acc[2][4] = {};
#pragma unroll
    for (int kk = 0; kk < 2; ++kk) {
        bh8 a[2], b[4];
#pragma unroll
        for (int am = 0; am < 2; ++am)
            a[am] = *(const bh8*)&Asm[wm * 32 + am * 16 + lr][kk * 32 + lk * 8];
#pragma unroll
        for (int bn = 0; bn < 4; ++bn)
            b[bn] = *(const bh8*)&Bsm[wn * 64 + bn * 16 + lr][kk * 32 + lk * 8];
#pragma unroll
        for (int am = 0; am < 2; ++am)
#pragma unroll
            for (int bn = 0; bn < 4; ++bn)
                acc[am][bn] = __builtin_amdgcn_mfma_f32_16x16x32_bf16(a[am], b[bn], acc[am][bn], 0, 0, 0);
    }
#pragma unroll
    for (int am = 0; am < 2; ++am)
#pragma unroll
        for (int bn = 0; bn < 4; ++bn) {
            int c = c0 + wn * 64 + bn * 16 + lr;
            if (c < 708) {
                float brow = biasrow[c];
#pragma unroll
                for (int q = 0; q < 4; ++q) {
                    int r = r0 + wm * 32 + am * 16 + lk * 4 + q;
                    if (r < N) {
                        float val = acc[am][bn][q] + brow;
                        if (c < 128) Xc[(size_t)r * 128 + c] = f2bf(val);
                        else if (c < 640) V[(size_t)r * 512 + (c - 128)] = f2bf(val * KSCL);
                        else if (c < 704) U[(size_t)r * 64 + (c - 640)] = f2bf(val * KSCL);
                        else E0[(size_t)r * 4 + (c - 704)] = exp2f(val * KSCL);
                    }
                }
            }
        }
}

// ---------------- CSR build ----------------------------------------------------------
__global__ void hist_kernel(const int* __restrict__ recv, int* __restrict__ deg, int E) {
    int e = blockIdx.x * 256 + threadIdx.x;
    if (e < E) atomicAdd(&deg[recv[e]], 1);
}

__global__ __launch_bounds__(1024) void scan1_kernel(const int* __restrict__ deg,
                                                     int* __restrict__ pre,
                                                     int* __restrict__ bsum, int N) {
    __shared__ int sm[1024];
    int b = blockIdx.x, t = threadIdx.x;
    int i = b * 1024 + t;
    int v = (i < N) ? deg[i] : 0;
    sm[t] = v;
    __syncthreads();
    for (int off = 1; off < 1024; off <<= 1) {
        int u = (t >= off) ? sm[t - off] : 0;
        __syncthreads();
        sm[t] += u;
        __syncthreads();
    }
    if (i < N) pre[i] = sm[t] - v;
    if (t == 1023) bsum[b] = sm[1023];
}

__global__ void scan2_kernel(int* __restrict__ bsum, int* __restrict__ boff, int nb) {
    int t = threadIdx.x;  // 64 threads, nb <= 64
    int own = (t < nb) ? bsum[t] : 0;
    int v = own;
#pragma unroll
    for (int off = 1; off < 64; off <<= 1) {
        int u = __shfl_up(v, off);
        if (t >= off) v += u;
    }
    if (t < nb) boff[t] = v - own;
    if (t == 63) boff[64] = v;
}

__global__ void scan3_kernel(const int* __restrict__ pre, const int* __restrict__ boff,
                             int* __restrict__ row_start, int* __restrict__ cursor, int N) {
    int i = blockIdx.x * 1024 + threadIdx.x;
    if (i < N) {
        int rsv = pre[i] + boff[i >> 10];
        row_start[i] = rsv;
        cursor[i] = rsv;
    }
    if (i == N) row_start[N] = boff[64];
}

// scatter writes fused (edge, sender) pairs -> en reads both with ONE load
__global__ void scatter_kernel(const int* __restrict__ recv, const int* __restrict__ senders,
                               int* __restrict__ cursor, int2* __restrict__ esp, int E) {
    int e = blockIdx.x * 256 + threadIdx.x;
    if (e < E) {
        int s = senders[e];
        int p = atomicAdd(&cursor[recv[e]], 1);
        esp[p] = make_int2(e, s);
    }
}

// ---------------- EN v9: R7 structure + rs/re-only rotation (2 extra live ints) ------
// Wave = node. Lane = (g,k16). Group g handles edge slot 8s+g and 8s+4+g; k16 = 8 ch.
__global__ __launch_bounds__(256, 3) void en_kernel(const int* __restrict__ row_start,
                                                    const int2* __restrict__ esp,
                                                    const float* __restrict__ edges,
                                                    const u16* __restrict__ Xc,
                                                    const u16* __restrict__ V,
                                                    const u16* __restrict__ Uu,
                                                    const float* __restrict__ E0,
                                                    const float* __restrict__ W_edge,
                                                    const float* __restrict__ b_edge,
                                                    u16* __restrict__ agg, int N) {
    __shared__ float Wl[2048];  // swizzled: (k, ch=8*k16+2i+b) at k*128+32*i+2*k16+b
    int t = threadIdx.x;
    for (int i = t; i < 2048; i += 256) {
        int k = i >> 7, ch = i & 127;
        int pos = (k << 7) | ((((ch >> 1) & 3) << 5) | (((ch >> 3) & 15) << 1) | (ch & 1));
        Wl[pos] = W_edge[i];
    }
    __syncthreads();
    int lane = t & 63, wid = t >> 6;
    int g = lane >> 4, k16 = lane & 15;
    int nw = blockIdx.x * 4 + wid;
    int NW = gridDim.x * 4;

#define IDX8(ea, sa, eb, sb, s_)                                            \
    {                                                                       \
        int ev = 0, sv = 0;                                                 \
        if (lane < 8) {                                                     \
            int jj = (s_)*8 + lane;                                         \
            if (jj >= deg) jj = deg - 1;                                    \
            int2 pv = esp[rs + jj];                                         \
            ev = pv.x; sv = pv.y;                                           \
        }                                                                   \
        ea = __shfl(ev, g); sa = __shfl(sv, g);                             \
        eb = __shfl(ev, 4 + g); sb = __shfl(sv, 4 + g);                     \
    }

#define LOADP(Xq, Uq, Eq, Zq, eI, sI)                                       \
    {                                                                       \
        Xq = *(const uint4*)(Xc + (size_t)(sI)*128 + 8 * k16);              \
        Uq = *(const uint2*)(Uu + (size_t)(sI)*64 + k16 * 4);               \
        Eq = edges[(size_t)(eI)*16 + k16];                                  \
        Zq = *(const float4*)(E0 + (size_t)(sI)*4);                         \
    }

#define COMP(Xq, Uq, Eq, Zq, act)                                           \
    {                                                                       \
        pf2 X0 = u2f2(Xq.x), X1 = u2f2(Xq.y), X2 = u2f2(Xq.z), X3 = u2f2(Xq.w); \
        float uh[4] = {bflo(Uq.x), bfhi(Uq.x), bflo(Uq.y), bfhi(Uq.y)};     \
        float e0a[4] = {Zq.x, Zq.y, Zq.z, Zq.w};                            \
        _Pragma("unroll") for (int h = 0; h < 4; ++h) {                     \
            pf2 p2 = {Eq * uh[h], 0.f};                                     \
            p2 = pkfma(X0, vr[h][0], p2); p2 = pkfma(X1, vr[h][1], p2);     \
            p2 = pkfma(X2, vr[h][2], p2); p2 = pkfma(X3, vr[h][3], p2);     \
            float p = dpp_red16(p2.x + p2.y);                               \
            float wh = (act) ? e0a[h] * exp2f(p) : 0.f;                     \
            Ss[h] += wh; aE[h] = fmaf(wh, Eq, aE[h]);                       \
            pf2 w2 = {wh, wh};                                              \
            aX[h][0] = pkfma(w2, X0, aX[h][0]);                             \
            aX[h][1] = pkfma(w2, X1, aX[h][1]);                             \
            aX[h][2] = pkfma(w2, X2, aX[h][2]);                             \
            aX[h][3] = pkfma(w2, X3, aX[h][3]);                             \
        }                                                                   \
    }

    int n = nw;
    if (n >= N) return;
    int rs = row_start[n];
    int re = row_start[n + 1];
    while (true) {
        int deg = re - rs;
        int n2 = n + NW;
        bool more = (n2 < N);
        int rs2 = rs, re2 = re;
        if (more) {  // issue next node's CSR bounds early; land during body
            rs2 = row_start[n2];
            re2 = row_start[n2 + 1];
        }
        const u16* Vr = V + (size_t)n * 512;
        pf2 vr[4][4];
#pragma unroll
        for (int h = 0; h < 4; ++h) {
            uint4 v = *(const uint4*)(Vr + h * 128 + 8 * k16);
            vr[h][0] = u2f2(v.x); vr[h][1] = u2f2(v.y);
            vr[h][2] = u2f2(v.z); vr[h][3] = u2f2(v.w);
        }
        pf2 aX[4][4] = {};
        float Ss[4] = {0.f, 0.f, 0.f, 0.f};
        float aE[4] = {0.f, 0.f, 0.f, 0.f};

        if (deg > 0) {
            int nst = (deg + 7) >> 3;
            int eA0, sA0, eA1, sA1, eB0, sB0, eB1, sB1;
            IDX8(eA0, sA0, eA1, sA1, 0);
            uint4 xP0, xP1; uint2 uP0, uP1; float eP0, eP1; float4 zP0, zP1;
            LOADP(xP0, uP0, eP0, zP0, eA0, sA0);
            LOADP(xP1, uP1, eP1, zP1, eA1, sA1);
            if (nst > 1) {
                IDX8(eB0, sB0, eB1, sB1, 1);
            } else {
                eB0 = eA0; sB0 = sA0; eB1 = eA1; sB1 = sA1;
            }
            for (int s = 0; s < nst; ++s) {
                uint4 xc0 = xP0, xc1 = xP1;
                uint2 uc0 = uP0, uc1 = uP1;
                float ec0 = eP0, ec1 = eP1;
                float4 zc0 = zP0, zc1 = zP1;
                int base = s * 8;
                if (s + 1 < nst) {
                    LOADP(xP0, uP0, eP0, zP0, eB0, sB0);
                    LOADP(xP1, uP1, eP1, zP1, eB1, sB1);
                    if (s + 2 < nst) IDX8(eB0, sB0, eB1, sB1, s + 2);
                }
                COMP(xc0, uc0, ec0, zc0, base + g < deg);
                COMP(xc1, uc1, ec1, zc1, base + 4 + g < deg);
            }
        }
        // cross-group reduce (sum over the 4 edge-groups)
#pragma unroll
        for (int h = 0; h < 4; ++h) {
#pragma unroll
            for (int i = 0; i < 4; ++i) {
                pf2 v = aX[h][i];
                v.x += __shfl_xor(v.x, 16); v.y += __shfl_xor(v.y, 16);
                v.x += __shfl_xor(v.x, 32); v.y += __shfl_xor(v.y, 32);
                aX[h][i] = v;
            }
            Ss[h] += __shfl_xor(Ss[h], 16); Ss[h] += __shfl_xor(Ss[h], 32);
            aE[h] += __shfl_xor(aE[h], 16); aE[h] += __shfl_xor(aE[h], 32);
        }
        // finalize: group g owns head g over the full k range
        pf2 axg[4];
#pragma unroll
        for (int i = 0; i < 4; ++i)
            axg[i] = g == 0 ? aX[0][i] : g == 1 ? aX[1][i] : g == 2 ? aX[2][i] : aX[3][i];
        float aEg = g == 0 ? aE[0] : g == 1 ? aE[1] : g == 2 ? aE[2] : aE[3];
        float Sg = g == 0 ? Ss[0] : g == 1 ? Ss[1] : g == 2 ? Ss[2] : Ss[3];
        const pf2* Wp = (const pf2*)Wl;
#pragma unroll
        for (int kk = 0; kk < 16; ++kk) {
            float a = __shfl(aEg, (g << 4) | kk);  // broadcast within own group
            pf2 a2 = {a, a};
            int base = (kk << 6) + k16;  // same addr across groups -> LDS broadcast
            axg[0] = pkfma(a2, Wp[base], axg[0]);
            axg[1] = pkfma(a2, Wp[base + 16], axg[1]);
            axg[2] = pkfma(a2, Wp[base + 32], axg[2]);
            axg[3] = pkfma(a2, Wp[base + 48], axg[3]);
        }
        {
            float inv = (deg > 0 && Sg > 0.f) ? 1.f / Sg : 0.f;
            float bes = (deg > 0) ? 1.f : 0.f;
            const float* br = &b_edge[8 * k16];
            u32 o0 = (u32)f2bf(axg[0].x * inv + bes * br[0]) |
                     ((u32)f2bf(axg[0].y * inv + bes * br[1]) << 16);
            u32 o1 = (u32)f2bf(axg[1].x * inv + bes * br[2]) |
                     ((u32)f2bf(axg[1].y * inv + bes * br[3]) << 16);
            u32 o2 = (u32)f2bf(axg[2].x * inv + bes * br[4]) |
                     ((u32)f2bf(axg[2].y * inv + bes * br[5]) << 16);
            u32 o3 = (u32)f2bf(axg[3].x * inv + bes * br[6]) |
                     ((u32)f2bf(axg[3].y * inv + bes * br[7]) << 16);
            uint4 st = {o0, o1, o2, o3};
            *(uint4*)(agg + (size_t)n * 512 + g * 128 + 8 * k16) = st;
        }
        if (!more) break;
        n = n2; rs = rs2; re = re2;
    }
#undef IDX8
#undef LOADP
#undef COMP
}

// ---------------- G3 (MFMA): out = relu(x + agg @ W_out + b_out) ---------------------
__global__ __launch_bounds__(256) void g3_kernel(const u16* __restrict__ Xc,
                                                 const u16* __restrict__ agg,
                                                 const u16* __restrict__ WoT,
                                                 const float* __restrict__ bout,
                                                 const int* __restrict__ avgflag,
                                                 float* __restrict__ out, int N) {
    int t = threadIdx.x;
    int r0 = blockIdx.x * 64;
    if (*avgflag) {
        for (int i = t; i < 64 * 128; i += 256) {
            int n = r0 + (i >> 7), j = i & 127;
            if (n < N) {
                float s = 0.f;
#pragma unroll
                for (int h = 0; h < 4; ++h) s += bf2f(agg[(size_t)n * 512 + h * 128 + j]);
                float v = bf2f(Xc[(size_t)n * 128 + j]) + 0.25f * s;
                out[(size_t)n * 128 + j] = v > 0.f ? v : 0.f;
            }
        }
        return;
    }
    __shared__ u16 Asm[64][72];
    __shared__ u16 Bsm[128][72];
    int lane = t & 63, wave = t >> 6;
    int wm = wave >> 1, wn = wave & 1;
    int lr = lane & 15, lk = lane >> 4;
    f4 acc[2][4] = {};
    for (int kb = 0; kb < 8; ++kb) {
        if (kb) __syncthreads();
        {
            int row = t >> 2, ks = (t & 3) * 16;
            int r = r0 + row;
            uint4 v0 = {0, 0, 0, 0}, v1 = {0, 0, 0, 0};
            if (r < N) {
                const u16* src = &agg[(size_t)r * 512 + kb * 64 + ks];
                v0 = *(const uint4*)src;
                v1 = *(const uint4*)(src + 8);
            }
            *(uint4*)&Asm[row][ks] = v0;
            *(uint4*)&Asm[row][ks + 8] = v1;
        }
        {
            int col = t >> 1, ks = (t & 1) * 32;
            const u16* src = &WoT[(size_t)col * 512 + kb * 64 + ks];
            uint4 v0 = *(const uint4*)src;
            uint4 v1 = *(const uint4*)(src + 8);
            uint4 v2 = *(const uint4*)(src + 16);
            uint4 v3 = *(const uint4*)(src + 24);
            *(uint4*)&Bsm[col][ks] = v0;
            *(uint4*)&Bsm[col][ks + 8] = v1;
            *(uint4*)&Bsm[col][ks + 16] = v2;
            *(uint4*)&Bsm[col][ks + 24] = v3;
        }
        __syncthreads();
#pragma unroll
        for (int kk = 0; kk < 2; ++kk) {
            bh8 a[2], b[4];
#pragma unroll
            for (int am = 0; am < 2; ++am)
                a[am] = *(const bh8*)&Asm[wm * 32 + am * 16 + lr][kk * 32 + lk * 8];
#pragma unroll
            for (int bn = 0; bn < 4; ++bn)
                b[bn] = *(const bh8*)&Bsm[wn * 64 + bn * 16 + lr][kk * 32 + lk * 8];
#pragma unroll
            for (int am = 0; am < 2; ++am)
#pragma unroll
                for (int bn = 0; bn < 4; ++bn)
                    acc[am][bn] = __builtin_amdgcn_mfma_f32_16x16x32_bf16(a[am], b[bn], acc[am][bn], 0, 0, 0);
        }
    }
#pragma unroll
    for (int am = 0; am < 2; ++am)
#pragma unroll
        for (int bn = 0; bn < 4; ++bn) {
            int c = wn * 64 + bn * 16 + lr;
            float bc = bout[c];
#pragma unroll
            for (int q = 0; q < 4; ++q) {
                int r = r0 + wm * 32 + am * 16 + lk * 4 + q;
                if (r < N) {
                    float v = acc[am][bn][q] + bc + bf2f(Xc[(size_t)r * 128 + c]);
                    out[(size_t)r * 128 + c] = v > 0.f ? v : 0.f;
                }
            }
        }
}

// ---------------- launch --------------------------------------------------------------
extern "C" void kernel_launch(void* const* d_in, const int* in_sizes, int n_in, void* d_out,
                              int out_size, void* d_ws, size_t ws_size, hipStream_t stream) {
    const float* nodes = (const float*)d_in[0];
    const float* edges = (const float*)d_in[1];
    const int* senders = (const int*)d_in[2];
    const int* receivers = (const int*)d_in[3];
    const int* avgflag = (const int*)d_in[4];
    const float* W_node = (const float*)d_in[5];
    const float* b_node = (const float*)d_in[6];
    const float* W_edge = (const float*)d_in[7];
    const float* b_edge = (const float*)d_in[8];
    const float* Wk_s = (const float*)d_in[9];
    const float* bk_s = (const float*)d_in[10];
    const float* Wk_r = (const float*)d_in[11];
    const float* bk_r = (const float*)d_in[12];
    const float* W_out = (const float*)d_in[13];
    const float* b_out = (const float*)d_in[14];
    int N = in_sizes[0] / 64;
    int E = in_sizes[2];
    float* outp = (float*)d_out;

    char* base = (char*)d_ws;
    size_t off = 0;
    auto alloc = [&](size_t nbytes) -> char* {
        char* p = base + off;
        off = (off + nbytes + 255) & ~(size_t)255;
        return p;
    };
    u16* Xc = (u16*)alloc((size_t)N * 128 * 2);
    u16* V = (u16*)alloc((size_t)N * 512 * 2);
    u16* U = (u16*)alloc((size_t)N * 64 * 2);
    float* E0 = (float*)alloc((size_t)N * 4 * 4);
    u16* agg = (u16*)alloc((size_t)N * 512 * 2);
    int* deg = (int*)alloc((size_t)N * 4);
    int* row_start = (int*)alloc((size_t)(N + 1) * 4);
    int* cursor = (int*)alloc((size_t)N * 4);
    int2* esp = (int2*)alloc((size_t)E * 8);
    int* pre = (int*)alloc((size_t)N * 4);
    int* bsum = (int*)alloc((size_t)128 * 4);
    int* boff = (int*)alloc((size_t)128 * 4);
    float* A = (float*)alloc((size_t)4 * 64 * 128 * 4);
    float* B = (float*)alloc((size_t)4 * 64 * 128 * 4);
    float* ybr = (float*)alloc((size_t)4 * 128 * 4);
    float* ybs = (float*)alloc((size_t)4 * 128 * 4);
    float* biasrow = (float*)alloc((size_t)712 * 4);
    u16* WfT = (u16*)alloc((size_t)768 * 64 * 2);
    u16* WoT = (u16*)alloc((size_t)128 * 512 * 2);

    int nb = (N + 1023) >> 10;

    hipMemsetAsync(deg, 0, (size_t)N * 4, stream);
    k0a_kernel<<<(132096 + 255) / 256, 256, 0, stream>>>(W_node, Wk_s, Wk_r, W_out, b_node,
                                                         bk_s, bk_r, A, B, WoT, ybs, ybr);
    k0b_kernel<<<(65 * 708 + 60 * 64 + 255) / 256, 256, 0, stream>>>(
        W_node, b_node, A, B, ybr, ybs, Wk_s, W_edge, bk_s, b_edge, WfT, biasrow);
    dim3 g1grid((N + 63) / 64, 6);
    g1_kernel<<<g1grid, 256, 0, stream>>>(nodes, WfT, biasrow, Xc, V, U, E0, N);
    hist_kernel<<<(E + 255) / 256, 256, 0, stream>>>(receivers, deg, E);
    scan1_kernel<<<nb, 1024, 0, stream>>>(deg, pre, bsum, N);
    scan2_kernel<<<1, 64, 0, stream>>>(bsum, boff, nb);
    scan3_kernel<<<(N + 1024) / 1024, 1024, 0, stream>>>(pre, boff, row_start, cursor, N);
    scatter_kernel<<<(E + 255) / 256, 256, 0, stream>>>(receivers, senders, cursor, esp, E);
    en_kernel<<<4096, 256, 0, stream>>>(row_start, esp, edges, Xc, V, U, E0, W_edge,
                                        b_edge, agg, N);
    g3_kernel<<<(N + 63) / 64, 256, 0, stream>>>(Xc, agg, WoT, b_out, avgflag, outp, N);
}

// Round 12
// 320.169 us; speedup vs baseline: 1.6325x; 1.0177x over previous
//
#include <hip/hip_runtime.h>

typedef unsigned short u16;
typedef unsigned int u32;
typedef short bh8 __attribute__((ext_vector_type(8)));   // 8 bf16 (A/B frag)
typedef float f4 __attribute__((ext_vector_type(4)));    // 4 f32 (C/D frag)
typedef float pf2 __attribute__((ext_vector_type(2)));   // packed f32 pair

__device__ __forceinline__ float bf2f(u16 h) { return __uint_as_float(((u32)h) << 16); }
__device__ __forceinline__ float bflo(u32 u) { return __uint_as_float(u << 16); }
__device__ __forceinline__ float bfhi(u32 u) { return __uint_as_float(u & 0xffff0000u); }
__device__ __forceinline__ u16 f2bf(float f) {
    u32 x = __float_as_uint(f);
    return (u16)((x + 0x7fffu + ((x >> 16) & 1u)) >> 16);  // RNE
}
__device__ __forceinline__ pf2 pkfma(pf2 a, pf2 b, pf2 c) {
    pf2 d;
    asm("v_pk_fma_f32 %0, %1, %2, %3" : "=v"(d) : "v"(a), "v"(b), "v"(c));
    return d;
}
__device__ __forceinline__ pf2 u2f2(u32 u) {
    pf2 r;
    r.x = bflo(u);
    r.y = bfhi(u);
    return r;
}
// 16-lane sum via DPP (VALU pipe, no LDS)
__device__ __forceinline__ float dpp_red16(float x) {
    int y;
    y = __builtin_amdgcn_update_dpp(0, __float_as_int(x), 0xB1, 0xF, 0xF, true);
    x += __int_as_float(y);
    y = __builtin_amdgcn_update_dpp(0, __float_as_int(x), 0x4E, 0xF, 0xF, true);
    x += __int_as_float(y);
    y = __builtin_amdgcn_update_dpp(0, __float_as_int(x), 0x141, 0xF, 0xF, true);
    x += __int_as_float(y);
    y = __builtin_amdgcn_update_dpp(0, __float_as_int(x), 0x140, 0xF, 0xF, true);
    x += __int_as_float(y);
    return x;
}

#define KSCL 0.12751744336457488f  // (1/sqrt(128)) * log2(e)

// ---------------- K0a: A_h = W_node@Wk_r[h], B_h = W_node@Wk_s[h], WoT, yb vectors ---
// idx < 65536: A/B.  [65536,131072): WoT transpose.  [131072,132096): ybs/ybr.
__global__ void k0a_kernel(const float* __restrict__ Wn, const float* __restrict__ Wks,
                           const float* __restrict__ Wkr, const float* __restrict__ Wout,
                           const float* __restrict__ bn, const float* __restrict__ bks,
                           const float* __restrict__ bkr, float* __restrict__ A,
                           float* __restrict__ B, u16* __restrict__ WoT,
                           float* __restrict__ ybs, float* __restrict__ ybr) {
    int idx = blockIdx.x * 256 + threadIdx.x;
    if (idx < 65536) {
        int which = idx >> 15;
        int rem = idx & 32767;
        int h = rem >> 13;
        int r = rem & 8191;
        int a = r >> 7, dp = r & 127;
        const float* W = which ? Wks : Wkr;
        float acc = 0.f;
        for (int d = 0; d < 128; ++d)
            acc += Wn[a * 128 + d] * W[(h * 128 + d) * 128 + dp];
        (which ? B : A)[(h * 64 + a) * 128 + dp] = acc;
    } else if (idx < 131072) {
        int j = idx - 65536;
        int c = j >> 9, k = j & 511;
        WoT[j] = f2bf(Wout[(size_t)k * 128 + c]);
    } else if (idx < 132096) {
        int j = idx - 131072;
        int which = j >> 9;
        int rem = j & 511;
        int h = rem >> 7, dp = rem & 127;
        const float* W = which ? Wks : Wkr;
        const float* b = which ? bks : bkr;
        float acc = b[h * 128 + dp];
        for (int d = 0; d < 128; ++d) acc += bn[d] * W[(h * 128 + d) * 128 + dp];
        (which ? ybs : ybr)[h * 128 + dp] = acc;
    }
}

// ---------------- K0b: assemble WfT [768 x 64] (bf16, transposed) + biasrow[708] -----
// col c: [0:128) x | [128:640) v(h,i) | [640:704) u k-major | [704:708) c0_h | [708:768)=0
__global__ void k0b_kernel(const float* __restrict__ Wn, const float* __restrict__ bn,
                           const float* __restrict__ A, const float* __restrict__ B,
                           const float* __restrict__ ybr, const float* __restrict__ ybs,
                           const float* __restrict__ Wks, const float* __restrict__ Wedge,
                           const float* __restrict__ bks, const float* __restrict__ bedge,
                           u16* __restrict__ WfT, float* __restrict__ biasrow) {
    int idx = blockIdx.x * 256 + threadIdx.x;  // 65*708 + 60*64 (zero tail)
    if (idx >= 65 * 708 + 60 * 64) return;
    if (idx >= 65 * 708) {
        int j = idx - 65 * 708;
        WfT[(708 + (j >> 6)) * 64 + (j & 63)] = 0;
        return;
    }
    int a = idx / 708, c = idx % 708;
    float val;
    if (c < 128) {
        val = (a < 64) ? Wn[a * 128 + c] : bn[c];
    } else if (c < 640) {
        int h = (c - 128) >> 7, i = (c - 128) & 127;
        const float* rv = (a < 64) ? &A[(h * 64 + a) * 128] : &ybr[h * 128];
        float s = 0.f;
        for (int d = 0; d < 128; ++d) s += rv[d] * Wks[(h * 128 + i) * 128 + d];
        val = s;
    } else if (c < 704) {
        int k = (c - 640) >> 2, h = (c - 640) & 3;
        const float* rv = (a < 64) ? &B[(h * 64 + a) * 128] : &ybs[h * 128];
        float s = 0.f;
        for (int d = 0; d < 128; ++d) s += rv[d] * Wedge[k * 128 + d];
        val = s;
    } else {
        int h = c - 704;
        const float* rv = (a < 64) ? &B[(h * 64 + a) * 128] : &ybs[h * 128];
        float s = 0.f;
        for (int d = 0; d < 128; ++d) s += rv[d] * bedge[d];
        val = s;
    }
    if (a < 64) WfT[(size_t)c * 64 + a] = f2bf(val);
    else biasrow[c] = val;
}

// ---------------- G1 (MFMA): split tables Xc[N,128], V[N,512](pre-scaled), U[N,64],
//                  E0[N,4] = exp2(kscl*c0) ------------------------------------------
__global__ __launch_bounds__(256) void g1_kernel(const float* __restrict__ nodes,
                                                 const u16* __restrict__ WfT,
                                                 const float* __restrict__ biasrow,
                                                 u16* __restrict__ Xc, u16* __restrict__ V,
                                                 u16* __restrict__ U, float* __restrict__ E0,
                                                 int N) {
    __shared__ u16 Asm[64][72];
    __shared__ u16 Bsm[128][72];
    int t = threadIdx.x;
    int r0 = blockIdx.x * 64, c0 = blockIdx.y * 128;
    {
        int row = t >> 2, cb = (t & 3) * 16;
        int r = r0 + row;
        u16 pk[16];
        if (r < N) {
            const float* src = &nodes[(size_t)r * 64 + cb];
#pragma unroll
            for (int q = 0; q < 16; ++q) pk[q] = f2bf(src[q]);
        } else {
#pragma unroll
            for (int q = 0; q < 16; ++q) pk[q] = 0;
        }
        *(uint4*)&Asm[row][cb] = *(const uint4*)&pk[0];
        *(uint4*)&Asm[row][cb + 8] = *(const uint4*)&pk[8];
    }
    {
        int col = t >> 1, ks = (t & 1) * 32;
        const u16* src = &WfT[(size_t)(c0 + col) * 64 + ks];
        uint4 v0 = *(const uint4*)src;
        uint4 v1 = *(const uint4*)(src + 8);
        uint4 v2 = *(const uint4*)(src + 16);
        uint4 v3 = *(const uint4*)(src + 24);
        *(uint4*)&Bsm[col][ks] = v0;
        *(uint4*)&Bsm[col][ks + 8] = v1;
        *(uint4*)&Bsm[col][ks + 16] = v2;
        *(uint4*)&Bsm[col][ks + 24] = v3;
    }
    __syncthreads();
    int lane = t & 63, wave = t >> 6;
    int wm = wave >> 1, wn = wave & 1;
    int lr = lane & 15, lk = lane >> 4;
    f4 acc[2][4] = {};
#pragma unroll
    for (int kk = 0; kk < 2; ++kk) {
        bh8 a[2], b[4];
#pragma unroll
        for (int am = 0; am < 2; ++am)
            a[am] = *(const bh8*)&Asm[wm * 32 + am * 16 + lr][kk * 32 + lk * 8];
#pragma unroll
        for (int bn = 0; bn < 4; ++bn)
            b[bn] = *(const bh8*)&Bsm[wn * 64 + bn * 16 + lr][kk * 32 + lk * 8];
#pragma unroll
        for (int am = 0; am < 2; ++am)
#pragma unroll
            for (int bn = 0; bn < 4; ++bn)
                acc[am][bn] = __builtin_amdgcn_mfma_f32_16x16x32_bf16(a[am], b[bn], acc[am][bn], 0, 0, 0);
    }
#pragma unroll
    for (int am = 0; am < 2; ++am)
#pragma unroll
        for (int bn = 0; bn < 4; ++bn) {
            int c = c0 + wn * 64 + bn * 16 + lr;
            if (c < 708) {
                float brow = biasrow[c];
#pragma unroll
                for (int q = 0; q < 4; ++q) {
                    int r = r0 + wm * 32 + am * 16 + lk * 4 + q;
                    if (r < N) {
                        float val = acc[am][bn][q] + brow;
                        if (c < 128) Xc[(size_t)r * 128 + c] = f2bf(val);
                        else if (c < 640) V[(size_t)r * 512 + (c - 128)] = f2bf(val * KSCL);
                        else if (c < 704) U[(size_t)r * 64 + (c - 640)] = f2bf(val * KSCL);
                        else E0[(size_t)r * 4 + (c - 704)] = exp2f(val * KSCL);
                    }
                }
            }
        }
}

// ---------------- CSR build ----------------------------------------------------------
__global__ void hist_kernel(const int* __restrict__ recv, int* __restrict__ deg, int E) {
    int e = blockIdx.x * 256 + threadIdx.x;
    if (e < E) atomicAdd(&deg[recv[e]], 1);
}

__global__ __launch_bounds__(1024) void scan1_kernel(const int* __restrict__ deg,
                                                     int* __restrict__ pre,
                                                     int* __restrict__ bsum, int N) {
    __shared__ int sm[1024];
    int b = blockIdx.x, t = threadIdx.x;
    int i = b * 1024 + t;
    int v = (i < N) ? deg[i] : 0;
    sm[t] = v;
    __syncthreads();
    for (int off = 1; off < 1024; off <<= 1) {
        int u = (t >= off) ? sm[t - off] : 0;
        __syncthreads();
        sm[t] += u;
        __syncthreads();
    }
    if (i < N) pre[i] = sm[t] - v;
    if (t == 1023) bsum[b] = sm[1023];
}

__global__ void scan2_kernel(int* __restrict__ bsum, int* __restrict__ boff, int nb) {
    int t = threadIdx.x;  // 64 threads, nb <= 64
    int own = (t < nb) ? bsum[t] : 0;
    int v = own;
#pragma unroll
    for (int off = 1; off < 64; off <<= 1) {
        int u = __shfl_up(v, off);
        if (t >= off) v += u;
    }
    if (t < nb) boff[t] = v - own;
    if (t == 63) boff[64] = v;
}

__global__ void scan3_kernel(const int* __restrict__ pre, const int* __restrict__ boff,
                             int* __restrict__ row_start, int* __restrict__ cursor, int N) {
    int i = blockIdx.x * 1024 + threadIdx.x;
    if (i < N) {
        int rsv = pre[i] + boff[i >> 10];
        row_start[i] = rsv;
        cursor[i] = rsv;
    }
    if (i == N) row_start[N] = boff[64];
}

// scatter: s_csr[p] = sender; eperm[p][16] = bf16 edge features in CSR order
// (removes the 51MB random edge gather from en — en reads edges SEQUENTIALLY)
__global__ void scatter_kernel(const int* __restrict__ recv, const int* __restrict__ senders,
                               const float* __restrict__ edges, int* __restrict__ cursor,
                               int* __restrict__ s_csr, u16* __restrict__ eperm, int E) {
    int e = blockIdx.x * 256 + threadIdx.x;
    if (e < E) {
        int s = senders[e];
        const float* src = &edges[(size_t)e * 16];
        u16 tmp[16];
#pragma unroll
        for (int k = 0; k < 16; ++k) tmp[k] = f2bf(src[k]);
        int p = atomicAdd(&cursor[recv[e]], 1);
        s_csr[p] = s;
        u16* dst = &eperm[(size_t)p * 16];
        *(uint4*)dst = *(const uint4*)&tmp[0];
        *(uint4*)(dst + 8) = *(const uint4*)&tmp[8];
    }
}

// ---------------- EN v10: R9 structure, sequential edge reads, s-only idx ------------
// Wave = node. Lane = (g,k16). Group g handles edge slot 8s+g and 8s+4+g; k16 = 8 ch.
__global__ __launch_bounds__(256, 3) void en_kernel(const int* __restrict__ row_start,
                                                    const int* __restrict__ s_csr,
                                                    const u16* __restrict__ eperm,
                                                    const u16* __restrict__ Xc,
                                                    const u16* __restrict__ V,
                                                    const u16* __restrict__ Uu,
                                                    const float* __restrict__ E0,
                                                    const float* __restrict__ W_edge,
                                                    const float* __restrict__ b_edge,
                                                    u16* __restrict__ agg, int N) {
    __shared__ float Wl[2048];  // swizzled: (k, ch=8*k16+2i+b) at k*128+32*i+2*k16+b
    int t = threadIdx.x;
    for (int i = t; i < 2048; i += 256) {
        int k = i >> 7, ch = i & 127;
        int pos = (k << 7) | ((((ch >> 1) & 3) << 5) | (((ch >> 3) & 15) << 1) | (ch & 1));
        Wl[pos] = W_edge[i];
    }
    __syncthreads();
    int lane = t & 63, wid = t >> 6;
    int g = lane >> 4, k16 = lane & 15;
    int nw = blockIdx.x * 4 + wid;
    int NW = gridDim.x * 4;

#define IDXS(sa, sb, s_)                                                    \
    {                                                                       \
        int sv = 0;                                                         \
        if (lane < 8) {                                                     \
            int jj = (s_)*8 + lane;                                         \
            if (jj >= deg) jj = deg - 1;                                    \
            sv = s_csr[rs + jj];                                            \
        }                                                                   \
        sa = __shfl(sv, g); sb = __shfl(sv, 4 + g);                         \
    }

#define LOADP(Xq, Uq, Zq, sI)                                               \
    {                                                                       \
        Xq = *(const uint4*)(Xc + (size_t)(sI)*128 + 8 * k16);              \
        Uq = *(const uint2*)(Uu + (size_t)(sI)*64 + k16 * 4);               \
        Zq = *(const float4*)(E0 + (size_t)(sI)*4);                         \
    }

#define ELOAD(Eq, slot)                                                     \
    {                                                                       \
        int _j = (slot);                                                    \
        if (_j > deg - 1) _j = deg - 1;                                     \
        Eq = bf2f(eperm[(size_t)(rs + _j) * 16 + k16]);                     \
    }

#define COMP(Xq, Uq, Eq, Zq, act)                                           \
    {                                                                       \
        pf2 X0 = u2f2(Xq.x), X1 = u2f2(Xq.y), X2 = u2f2(Xq.z), X3 = u2f2(Xq.w); \
        float uh[4] = {bflo(Uq.x), bfhi(Uq.x), bflo(Uq.y), bfhi(Uq.y)};     \
        float e0a[4] = {Zq.x, Zq.y, Zq.z, Zq.w};                            \
        _Pragma("unroll") for (int h = 0; h < 4; ++h) {                     \
            pf2 p2 = {Eq * uh[h], 0.f};                                     \
            p2 = pkfma(X0, vr[h][0], p2); p2 = pkfma(X1, vr[h][1], p2);     \
            p2 = pkfma(X2, vr[h][2], p2); p2 = pkfma(X3, vr[h][3], p2);     \
            float p = dpp_red16(p2.x + p2.y);                               \
            float wh = (act) ? e0a[h] * exp2f(p) : 0.f;                     \
            Ss[h] += wh; aE[h] = fmaf(wh, Eq, aE[h]);                       \
            pf2 w2 = {wh, wh};                                              \
            aX[h][0] = pkfma(w2, X0, aX[h][0]);                             \
            aX[h][1] = pkfma(w2, X1, aX[h][1]);                             \
            aX[h][2] = pkfma(w2, X2, aX[h][2]);                             \
            aX[h][3] = pkfma(w2, X3, aX[h][3]);                             \
        }                                                                   \
    }

    int n = nw;
    if (n >= N) return;
    int rs = row_start[n];
    int re = row_start[n + 1];
    while (true) {
        int deg = re - rs;
        int n2 = n + NW;
        bool more = (n2 < N);
        int rs2 = rs, re2 = re;
        if (more) {  // issue next node's CSR bounds early; land during body
            rs2 = row_start[n2];
            re2 = row_start[n2 + 1];
        }
        const u16* Vr = V + (size_t)n * 512;
        pf2 vr[4][4];
#pragma unroll
        for (int h = 0; h < 4; ++h) {
            uint4 v = *(const uint4*)(Vr + h * 128 + 8 * k16);
            vr[h][0] = u2f2(v.x); vr[h][1] = u2f2(v.y);
            vr[h][2] = u2f2(v.z); vr[h][3] = u2f2(v.w);
        }
        pf2 aX[4][4] = {};
        float Ss[4] = {0.f, 0.f, 0.f, 0.f};
        float aE[4] = {0.f, 0.f, 0.f, 0.f};

        if (deg > 0) {
            int nst = (deg + 7) >> 3;
            int sA0, sA1, sB0, sB1;
            IDXS(sA0, sA1, 0);
            uint4 xP0, xP1; uint2 uP0, uP1; float4 zP0, zP1; float eP0, eP1;
            LOADP(xP0, uP0, zP0, sA0);
            LOADP(xP1, uP1, zP1, sA1);
            ELOAD(eP0, g);
            ELOAD(eP1, 4 + g);
            if (nst > 1) {
                IDXS(sB0, sB1, 1);
            } else {
                sB0 = sA0; sB1 = sA1;
            }
            for (int s = 0; s < nst; ++s) {
                uint4 xc0 = xP0, xc1 = xP1;
                uint2 uc0 = uP0, uc1 = uP1;
                float ec0 = eP0, ec1 = eP1;
                float4 zc0 = zP0, zc1 = zP1;
                int base = s * 8;
                if (s + 1 < nst) {
                    LOADP(xP0, uP0, zP0, sB0);
                    LOADP(xP1, uP1, zP1, sB1);
                    ELOAD(eP0, base + 8 + g);
                    ELOAD(eP1, base + 12 + g);
                    if (s + 2 < nst) IDXS(sB0, sB1, s + 2);
                }
                COMP(xc0, uc0, ec0, zc0, base + g < deg);
                COMP(xc1, uc1, ec1, zc1, base + 4 + g < deg);
            }
        }
        // cross-group reduce (sum over the 4 edge-groups)
#pragma unroll
        for (int h = 0; h < 4; ++h) {
#pragma unroll
            for (int i = 0; i < 4; ++i) {
                pf2 v = aX[h][i];
                v.x += __shfl_xor(v.x, 16); v.y += __shfl_xor(v.y, 16);
                v.x += __shfl_xor(v.x, 32); v.y += __shfl_xor(v.y, 32);
                aX[h][i] = v;
            }
            Ss[h] += __shfl_xor(Ss[h], 16); Ss[h] += __shfl_xor(Ss[h], 32);
            aE[h] += __shfl_xor(aE[h], 16); aE[h] += __shfl_xor(aE[h], 32);
        }
        // finalize: group g owns head g over the full k range
        pf2 axg[4];
#pragma unroll
        for (int i = 0; i < 4; ++i)
            axg[i] = g == 0 ? aX[0][i] : g == 1 ? aX[1][i] : g == 2 ? aX[2][i] : aX[3][i];
        float aEg = g == 0 ? aE[0] : g == 1 ? aE[1] : g == 2 ? aE[2] : aE[3];
        float Sg = g == 0 ? Ss[0] : g == 1 ? Ss[1] : g == 2 ? Ss[2] : Ss[3];
        const pf2* Wp = (const pf2*)Wl;
#pragma unroll
        for (int kk = 0; kk < 16; ++kk) {
            float a = __shfl(aEg, (g << 4) | kk);  // broadcast within own group
            pf2 a2 = {a, a};
            int base = (kk << 6) + k16;  // same addr across groups -> LDS broadcast
            axg[0] = pkfma(a2, Wp[base], axg[0]);
            axg[1] = pkfma(a2, Wp[base + 16], axg[1]);
            axg[2] = pkfma(a2, Wp[base + 32], axg[2]);
            axg[3] = pkfma(a2, Wp[base + 48], axg[3]);
        }
        {
            float inv = (deg > 0 && Sg > 0.f) ? 1.f / Sg : 0.f;
            float bes = (deg > 0) ? 1.f : 0.f;
            const float* br = &b_edge[8 * k16];
            u32 o0 = (u32)f2bf(axg[0].x * inv + bes * br[0]) |
                     ((u32)f2bf(axg[0].y * inv + bes * br[1]) << 16);
            u32 o1 = (u32)f2bf(axg[1].x * inv + bes * br[2]) |
                     ((u32)f2bf(axg[1].y * inv + bes * br[3]) << 16);
            u32 o2 = (u32)f2bf(axg[2].x * inv + bes * br[4]) |
                     ((u32)f2bf(axg[2].y * inv + bes * br[5]) << 16);
            u32 o3 = (u32)f2bf(axg[3].x * inv + bes * br[6]) |
                     ((u32)f2bf(axg[3].y * inv + bes * br[7]) << 16);
            uint4 st = {o0, o1, o2, o3};
            *(uint4*)(agg + (size_t)n * 512 + g * 128 + 8 * k16) = st;
        }
        if (!more) break;
        n = n2; rs = rs2; re = re2;
    }
#undef IDXS
#undef LOADP
#undef ELOAD
#undef COMP
}

// ---------------- G3 (MFMA): out = relu(x + agg @ W_out + b_out) ---------------------
__global__ __launch_bounds__(256) void g3_kernel(const u16* __restrict__ Xc,
                                                 const u16* __restrict__ agg,
                                                 const u16* __restrict__ WoT,
                                                 const float* __restrict__ bout,
                                                 const int* __restrict__ avgflag,
                                                 float* __restrict__ out, int N) {
    int t = threadIdx.x;
    int r0 = blockIdx.x * 64;
    if (*avgflag) {
        for (int i = t; i < 64 * 128; i += 256) {
            int n = r0 + (i >> 7), j = i & 127;
            if (n < N) {
                float s = 0.f;
#pragma unroll
                for (int h = 0; h < 4; ++h) s += bf2f(agg[(size_t)n * 512 + h * 128 + j]);
                float v = bf2f(Xc[(size_t)n * 128 + j]) + 0.25f * s;
                out[(size_t)n * 128 + j] = v > 0.f ? v : 0.f;
            }
        }
        return;
    }
    __shared__ u16 Asm[64][72];
    __shared__ u16 Bsm[128][72];
    int lane = t & 63, wave = t >> 6;
    int wm = wave >> 1, wn = wave & 1;
    int lr = lane & 15, lk = lane >> 4;
    f4 acc[2][4] = {};
    for (int kb = 0; kb < 8; ++kb) {
        if (kb) __syncthreads();
        {
            int row = t >> 2, ks = (t & 3) * 16;
            int r = r0 + row;
            uint4 v0 = {0, 0, 0, 0}, v1 = {0, 0, 0, 0};
            if (r < N) {
                const u16* src = &agg[(size_t)r * 512 + kb * 64 + ks];
                v0 = *(const uint4*)src;
                v1 = *(const uint4*)(src + 8);
            }
            *(uint4*)&Asm[row][ks] = v0;
            *(uint4*)&Asm[row][ks + 8] = v1;
        }
        {
            int col = t >> 1, ks = (t & 1) * 32;
            const u16* src = &WoT[(size_t)col * 512 + kb * 64 + ks];
            uint4 v0 = *(const uint4*)src;
            uint4 v1 = *(const uint4*)(src + 8);
            uint4 v2 = *(const uint4*)(src + 16);
            uint4 v3 = *(const uint4*)(src + 24);
            *(uint4*)&Bsm[col][ks] = v0;
            *(uint4*)&Bsm[col][ks + 8] = v1;
            *(uint4*)&Bsm[col][ks + 16] = v2;
            *(uint4*)&Bsm[col][ks + 24] = v3;
        }
        __syncthreads();
#pragma unroll
        for (int kk = 0; kk < 2; ++kk) {
            bh8 a[2], b[4];
#pragma unroll
            for (int am = 0; am < 2; ++am)
                a[am] = *(const bh8*)&Asm[wm * 32 + am * 16 + lr][kk * 32 + lk * 8];
#pragma unroll
            for (int bn = 0; bn < 4; ++bn)
                b[bn] = *(const bh8*)&Bsm[wn * 64 + bn * 16 + lr][kk * 32 + lk * 8];
#pragma unroll
            for (int am = 0; am < 2; ++am)
#pragma unroll
                for (int bn = 0; bn < 4; ++bn)
                    acc[am][bn] = __builtin_amdgcn_mfma_f32_16x16x32_bf16(a[am], b[bn], acc[am][bn], 0, 0, 0);
        }
    }
#pragma unroll
    for (int am = 0; am < 2; ++am)
#pragma unroll
        for (int bn = 0; bn < 4; ++bn) {
            int c = wn * 64 + bn * 16 + lr;
            float bc = bout[c];
#pragma unroll
            for (int q = 0; q < 4; ++q) {
                int r = r0 + wm * 32 + am * 16 + lk * 4 + q;
                if (r < N) {
                    float v = acc[am][bn][q] + bc + bf2f(Xc[(size_t)r * 128 + c]);
                    out[(size_t)r * 128 + c] = v > 0.f ? v : 0.f;
                }
            }
        }
}

// ---------------- launch --------------------------------------------------------------
extern "C" void kernel_launch(void* const* d_in, const int* in_sizes, int n_in, void* d_out,
                              int out_size, void* d_ws, size_t ws_size, hipStream_t stream) {
    const float* nodes = (const float*)d_in[0];
    const float* edges = (const float*)d_in[1];
    const int* senders = (const int*)d_in[2];
    const int* receivers = (const int*)d_in[3];
    const int* avgflag = (const int*)d_in[4];
    const float* W_node = (const float*)d_in[5];
    const float* b_node = (const float*)d_in[6];
    const float* W_edge = (const float*)d_in[7];
    const float* b_edge = (const float*)d_in[8];
    const float* Wk_s = (const float*)d_in[9];
    const float* bk_s = (const float*)d_in[10];
    const float* Wk_r = (const float*)d_in[11];
    const float* bk_r = (const float*)d_in[12];
    const float* W_out = (const float*)d_in[13];
    const float* b_out = (const float*)d_in[14];
    int N = in_sizes[0] / 64;
    int E = in_sizes[2];
    float* outp = (float*)d_out;

    char* base = (char*)d_ws;
    size_t off = 0;
    auto alloc = [&](size_t nbytes) -> char* {
        char* p = base + off;
        off = (off + nbytes + 255) & ~(size_t)255;
        return p;
    };
    u16* Xc = (u16*)alloc((size_t)N * 128 * 2);
    u16* V = (u16*)alloc((size_t)N * 512 * 2);
    u16* U = (u16*)alloc((size_t)N * 64 * 2);
    float* E0 = (float*)alloc((size_t)N * 4 * 4);
    u16* agg = (u16*)alloc((size_t)N * 512 * 2);
    int* deg = (int*)alloc((size_t)N * 4);
    int* row_start = (int*)alloc((size_t)(N + 1) * 4);
    int* cursor = (int*)alloc((size_t)N * 4);
    int* s_csr = (int*)alloc((size_t)E * 4);
    u16* eperm = (u16*)alloc((size_t)E * 16 * 2);
    int* pre = (int*)alloc((size_t)N * 4);
    int* bsum = (int*)alloc((size_t)128 * 4);
    int* boff = (int*)alloc((size_t)128 * 4);
    float* A = (float*)alloc((size_t)4 * 64 * 128 * 4);
    float* B = (float*)alloc((size_t)4 * 64 * 128 * 4);
    float* ybr = (float*)alloc((size_t)4 * 128 * 4);
    float* ybs = (float*)alloc((size_t)4 * 128 * 4);
    float* biasrow = (float*)alloc((size_t)712 * 4);
    u16* WfT = (u16*)alloc((size_t)768 * 64 * 2);
    u16* WoT = (u16*)alloc((size_t)128 * 512 * 2);

    int nb = (N + 1023) >> 10;

    hipMemsetAsync(deg, 0, (size_t)N * 4, stream);
    k0a_kernel<<<(132096 + 255) / 256, 256, 0, stream>>>(W_node, Wk_s, Wk_r, W_out, b_node,
                                                         bk_s, bk_r, A, B, WoT, ybs, ybr);
    k0b_kernel<<<(65 * 708 + 60 * 64 + 255) / 256, 256, 0, stream>>>(
        W_node, b_node, A, B, ybr, ybs, Wk_s, W_edge, bk_s, b_edge, WfT, biasrow);
    dim3 g1grid((N + 63) / 64, 6);
    g1_kernel<<<g1grid, 256, 0, stream>>>(nodes, WfT, biasrow, Xc, V, U, E0, N);
    hist_kernel<<<(E + 255) / 256, 256, 0, stream>>>(receivers, deg, E);
    scan1_kernel<<<nb, 1024, 0, stream>>>(deg, pre, bsum, N);
    scan2_kernel<<<1, 64, 0, stream>>>(bsum, boff, nb);
    scan3_kernel<<<(N + 1024) / 1024, 1024, 0, stream>>>(pre, boff, row_start, cursor, N);
    scatter_kernel<<<(E + 255) / 256, 256, 0, stream>>>(receivers, senders, edges, cursor,
                                                        s_csr, eperm, E);
    en_kernel<<<4096, 256, 0, stream>>>(row_start, s_csr, eperm, Xc, V, U, E0, W_edge,
                                        b_edge, agg, N);
    g3_kernel<<<(N + 63) / 64, 256, 0, stream>>>(Xc, agg, WoT, b_out, avgflag, outp, N);
}

// Round 13
// 315.277 us; speedup vs baseline: 1.6578x; 1.0155x over previous
//
#include <hip/hip_runtime.h>

typedef unsigned short u16;
typedef unsigned int u32;
typedef short bh8 __attribute__((ext_vector_type(8)));   // 8 bf16 (A/B frag)
typedef float f4 __attribute__((ext_vector_type(4)));    // 4 f32 (C/D frag)
typedef float pf2 __attribute__((ext_vector_type(2)));   // packed f32 pair

__device__ __forceinline__ float bf2f(u16 h) { return __uint_as_float(((u32)h) << 16); }
__device__ __forceinline__ float bflo(u32 u) { return __uint_as_float(u << 16); }
__device__ __forceinline__ float bfhi(u32 u) { return __uint_as_float(u & 0xffff0000u); }
__device__ __forceinline__ u16 f2bf(float f) {
    u32 x = __float_as_uint(f);
    return (u16)((x + 0x7fffu + ((x >> 16) & 1u)) >> 16);  // RNE
}
__device__ __forceinline__ pf2 pkfma(pf2 a, pf2 b, pf2 c) {
    pf2 d;
    asm("v_pk_fma_f32 %0, %1, %2, %3" : "=v"(d) : "v"(a), "v"(b), "v"(c));
    return d;
}
__device__ __forceinline__ pf2 u2f2(u32 u) {
    pf2 r;
    r.x = bflo(u);
    r.y = bfhi(u);
    return r;
}
// 16-lane sum via DPP (VALU pipe, no LDS)
__device__ __forceinline__ float dpp_red16(float x) {
    int y;
    y = __builtin_amdgcn_update_dpp(0, __float_as_int(x), 0xB1, 0xF, 0xF, true);
    x += __int_as_float(y);
    y = __builtin_amdgcn_update_dpp(0, __float_as_int(x), 0x4E, 0xF, 0xF, true);
    x += __int_as_float(y);
    y = __builtin_amdgcn_update_dpp(0, __float_as_int(x), 0x141, 0xF, 0xF, true);
    x += __int_as_float(y);
    y = __builtin_amdgcn_update_dpp(0, __float_as_int(x), 0x140, 0xF, 0xF, true);
    x += __int_as_float(y);
    return x;
}

#define KSCL 0.12751744336457488f  // (1/sqrt(128)) * log2(e)

// ---------------- K0a: A_h = W_node@Wk_r[h], B_h = W_node@Wk_s[h], WoT, yb vectors ---
// idx < 65536: A/B.  [65536,131072): WoT transpose.  [131072,132096): ybs/ybr.
__global__ void k0a_kernel(const float* __restrict__ Wn, const float* __restrict__ Wks,
                           const float* __restrict__ Wkr, const float* __restrict__ Wout,
                           const float* __restrict__ bn, const float* __restrict__ bks,
                           const float* __restrict__ bkr, float* __restrict__ A,
                           float* __restrict__ B, u16* __restrict__ WoT,
                           float* __restrict__ ybs, float* __restrict__ ybr) {
    int idx = blockIdx.x * 256 + threadIdx.x;
    if (idx < 65536) {
        int which = idx >> 15;
        int rem = idx & 32767;
        int h = rem >> 13;
        int r = rem & 8191;
        int a = r >> 7, dp = r & 127;
        const float* W = which ? Wks : Wkr;
        float acc = 0.f;
        for (int d = 0; d < 128; ++d)
            acc += Wn[a * 128 + d] * W[(h * 128 + d) * 128 + dp];
        (which ? B : A)[(h * 64 + a) * 128 + dp] = acc;
    } else if (idx < 131072) {
        int j = idx - 65536;
        int c = j >> 9, k = j & 511;
        WoT[j] = f2bf(Wout[(size_t)k * 128 + c]);
    } else if (idx < 132096) {
        int j = idx - 131072;
        int which = j >> 9;
        int rem = j & 511;
        int h = rem >> 7, dp = rem & 127;
        const float* W = which ? Wks : Wkr;
        const float* b = which ? bks : bkr;
        float acc = b[h * 128 + dp];
        for (int d = 0; d < 128; ++d) acc += bn[d] * W[(h * 128 + d) * 128 + dp];
        (which ? ybs : ybr)[h * 128 + dp] = acc;
    }
}

// ---------------- K0b: assemble WfT [768 x 64] (bf16, transposed) + biasrow[708] -----
// col c: [0:128) x | [128:640) v(h,i) | [640:704) u k-major | [704:708) c0_h | [708:768)=0
__global__ void k0b_kernel(const float* __restrict__ Wn, const float* __restrict__ bn,
                           const float* __restrict__ A, const float* __restrict__ B,
                           const float* __restrict__ ybr, const float* __restrict__ ybs,
                           const float* __restrict__ Wks, const float* __restrict__ Wedge,
                           const float* __restrict__ bks, const float* __restrict__ bedge,
                           u16* __restrict__ WfT, float* __restrict__ biasrow) {
    int idx = blockIdx.x * 256 + threadIdx.x;  // 65*708 + 60*64 (zero tail)
    if (idx >= 65 * 708 + 60 * 64) return;
    if (idx >= 65 * 708) {
        int j = idx - 65 * 708;
        WfT[(708 + (j >> 6)) * 64 + (j & 63)] = 0;
        return;
    }
    int a = idx / 708, c = idx % 708;
    float val;
    if (c < 128) {
        val = (a < 64) ? Wn[a * 128 + c] : bn[c];
    } else if (c < 640) {
        int h = (c - 128) >> 7, i = (c - 128) & 127;
        const float* rv = (a < 64) ? &A[(h * 64 + a) * 128] : &ybr[h * 128];
        float s = 0.f;
        for (int d = 0; d < 128; ++d) s += rv[d] * Wks[(h * 128 + i) * 128 + d];
        val = s;
    } else if (c < 704) {
        int k = (c - 640) >> 2, h = (c - 640) & 3;
        const float* rv = (a < 64) ? &B[(h * 64 + a) * 128] : &ybs[h * 128];
        float s = 0.f;
        for (int d = 0; d < 128; ++d) s += rv[d] * Wedge[k * 128 + d];
        val = s;
    } else {
        int h = c - 704;
        const float* rv = (a < 64) ? &B[(h * 64 + a) * 128] : &ybs[h * 128];
        float s = 0.f;
        for (int d = 0; d < 128; ++d) s += rv[d] * bedge[d];
        val = s;
    }
    if (a < 64) WfT[(size_t)c * 64 + a] = f2bf(val);
    else biasrow[c] = val;
}

// ---------------- G1 (MFMA): split tables Xc[N,128], V[N,512](pre-scaled), U[N,64],
//                  E0[N,4] = exp2(kscl*c0) ------------------------------------------
__global__ __launch_bounds__(256) void g1_kernel(const float* __restrict__ nodes,
                                                 const u16* __restrict__ WfT,
                                                 const float* __restrict__ biasrow,
                                                 u16* __restrict__ Xc, u16* __restrict__ V,
                                                 u16* __restrict__ U, float* __restrict__ E0,
                                                 int N) {
    __shared__ u16 Asm[64][72];
    __shared__ u16 Bsm[128][72];
    int t = threadIdx.x;
    int r0 = blockIdx.x * 64, c0 = blockIdx.y * 128;
    {
        int row = t >> 2, cb = (t & 3) * 16;
        int r = r0 + row;
        u16 pk[16];
        if (r < N) {
            const float* src = &nodes[(size_t)r * 64 + cb];
#pragma unroll
            for (int q = 0; q < 16; ++q) pk[q] = f2bf(src[q]);
        } else {
#pragma unroll
            for (int q = 0; q < 16; ++q) pk[q] = 0;
        }
        *(uint4*)&Asm[row][cb] = *(const uint4*)&pk[0];
        *(uint4*)&Asm[row][cb + 8] = *(const uint4*)&pk[8];
    }
    {
        int col = t >> 1, ks = (t & 1) * 32;
        const u16* src = &WfT[(size_t)(c0 + col) * 64 + ks];
        uint4 v0 = *(const uint4*)src;
        uint4 v1 = *(const uint4*)(src + 8);
        uint4 v2 = *(const uint4*)(src + 16);
        uint4 v3 = *(const uint4*)(src + 24);
        *(uint4*)&Bsm[col][ks] = v0;
        *(uint4*)&Bsm[col][ks + 8] = v1;
        *(uint4*)&Bsm[col][ks + 16] = v2;
        *(uint4*)&Bsm[col][ks + 24] = v3;
    }
    __syncthreads();
    int lane = t & 63, wave = t >> 6;
    int wm = wave >> 1, wn = wave & 1;
    int lr = lane & 15, lk = lane >> 4;
    f4 acc[2][4] = {};
#pragma unroll
    for (int kk = 0; kk < 2; ++kk) {
        bh8 a[2], b[4];
#pragma unroll
        for (int am = 0; am < 2; ++am)
            a[am] = *(const bh8*)&Asm[wm * 32 + am * 16 + lr][kk * 32 + lk * 8];
#pragma unroll
        for (int bn = 0; bn < 4; ++bn)
            b[bn] = *(const bh8*)&Bsm[wn * 64 + bn * 16 + lr][kk * 32 + lk * 8];
#pragma unroll
        for (int am = 0; am < 2; ++am)
#pragma unroll
            for (int bn = 0; bn < 4; ++bn)
                acc[am][bn] = __builtin_amdgcn_mfma_f32_16x16x32_bf16(a[am], b[bn], acc[am][bn], 0, 0, 0);
    }
#pragma unroll
    for (int am = 0; am < 2; ++am)
#pragma unroll
        for (int bn = 0; bn < 4; ++bn) {
            int c = c0 + wn * 64 + bn * 16 + lr;
            if (c < 708) {
                float brow = biasrow[c];
#pragma unroll
                for (int q = 0; q < 4; ++q) {
                    int r = r0 + wm * 32 + am * 16 + lk * 4 + q;
                    if (r < N) {
                        float val = acc[am][bn][q] + brow;
                        if (c < 128) Xc[(size_t)r * 128 + c] = f2bf(val);
                        else if (c < 640) V[(size_t)r * 512 + (c - 128)] = f2bf(val * KSCL);
                        else if (c < 704) U[(size_t)r * 64 + (c - 640)] = f2bf(val * KSCL);
                        else E0[(size_t)r * 4 + (c - 704)] = __builtin_amdgcn_exp2f(val * KSCL);
                    }
                }
            }
        }
}

// ---------------- CSR build ----------------------------------------------------------
__global__ void hist_kernel(const int* __restrict__ recv, int* __restrict__ deg, int E) {
    int e = blockIdx.x * 256 + threadIdx.x;
    if (e < E) atomicAdd(&deg[recv[e]], 1);
}

__global__ __launch_bounds__(1024) void scan1_kernel(const int* __restrict__ deg,
                                                     int* __restrict__ pre,
                                                     int* __restrict__ bsum, int N) {
    __shared__ int sm[1024];
    int b = blockIdx.x, t = threadIdx.x;
    int i = b * 1024 + t;
    int v = (i < N) ? deg[i] : 0;
    sm[t] = v;
    __syncthreads();
    for (int off = 1; off < 1024; off <<= 1) {
        int u = (t >= off) ? sm[t - off] : 0;
        __syncthreads();
        sm[t] += u;
        __syncthreads();
    }
    if (i < N) pre[i] = sm[t] - v;
    if (t == 1023) bsum[b] = sm[1023];
}

__global__ void scan2_kernel(int* __restrict__ bsum, int* __restrict__ boff, int nb) {
    int t = threadIdx.x;  // 64 threads, nb <= 64
    int own = (t < nb) ? bsum[t] : 0;
    int v = own;
#pragma unroll
    for (int off = 1; off < 64; off <<= 1) {
        int u = __shfl_up(v, off);
        if (t >= off) v += u;
    }
    if (t < nb) boff[t] = v - own;
    if (t == 63) boff[64] = v;
}

__global__ void scan3_kernel(const int* __restrict__ pre, const int* __restrict__ boff,
                             int* __restrict__ row_start, int* __restrict__ cursor, int N) {
    int i = blockIdx.x * 1024 + threadIdx.x;
    if (i < N) {
        int rsv = pre[i] + boff[i >> 10];
        row_start[i] = rsv;
        cursor[i] = rsv;
    }
    if (i == N) row_start[N] = boff[64];
}

// scatter: s_csr[p] = sender; eperm[p][16] = bf16 edge features in CSR order
__global__ void scatter_kernel(const int* __restrict__ recv, const int* __restrict__ senders,
                               const float* __restrict__ edges, int* __restrict__ cursor,
                               int* __restrict__ s_csr, u16* __restrict__ eperm, int E) {
    int e = blockIdx.x * 256 + threadIdx.x;
    if (e < E) {
        int s = senders[e];
        const float* src = &edges[(size_t)e * 16];
        u16 tmp[16];
#pragma unroll
        for (int k = 0; k < 16; ++k) tmp[k] = f2bf(src[k]);
        int p = atomicAdd(&cursor[recv[e]], 1);
        s_csr[p] = s;
        u16* dst = &eperm[(size_t)p * 16];
        *(uint4*)dst = *(const uint4*)&tmp[0];
        *(uint4*)(dst + 8) = *(const uint4*)&tmp[8];
    }
}

// ---------------- EN v11: R10 structure + 32-bit addressing + raw v_exp_f32 ----------
// Wave = node. Lane = (g,k16). Group g handles edge slot 8s+g and 8s+4+g; k16 = 8 ch.
__global__ __launch_bounds__(256, 3) void en_kernel(const int* __restrict__ row_start,
                                                    const int* __restrict__ s_csr,
                                                    const u16* __restrict__ eperm,
                                                    const u16* __restrict__ Xc,
                                                    const u16* __restrict__ V,
                                                    const u16* __restrict__ Uu,
                                                    const float* __restrict__ E0,
                                                    const float* __restrict__ W_edge,
                                                    const float* __restrict__ b_edge,
                                                    u16* __restrict__ agg, int N) {
    __shared__ float Wl[2048];  // swizzled: (k, ch=8*k16+2i+b) at k*128+32*i+2*k16+b
    int t = threadIdx.x;
    for (int i = t; i < 2048; i += 256) {
        int k = i >> 7, ch = i & 127;
        int pos = (k << 7) | ((((ch >> 1) & 3) << 5) | (((ch >> 3) & 15) << 1) | (ch & 1));
        Wl[pos] = W_edge[i];
    }
    __syncthreads();
    int lane = t & 63, wid = t >> 6;
    int g = lane >> 4, k16 = lane & 15;
    int nw = blockIdx.x * 4 + wid;
    int NW = gridDim.x * 4;

    const char* XcB = (const char*)Xc;
    const char* UuB = (const char*)Uu;
    const char* E0B = (const char*)E0;
    const char* epB = (const char*)eperm;
    const char* scB = (const char*)s_csr;
    const u32 xl = (u32)k16 << 4;  // lane offsets
    const u32 ul = (u32)k16 << 3;
    const u32 el = (u32)k16 << 1;

#define IDXS(sa, sb, s_)                                                    \
    {                                                                       \
        int sv = 0;                                                         \
        if (lane < 8) {                                                     \
            int jj = (s_)*8 + lane;                                         \
            if (jj >= deg) jj = deg - 1;                                    \
            sv = *(const int*)(scB + (((u32)(rs + jj)) << 2));              \
        }                                                                   \
        sa = __shfl(sv, g); sb = __shfl(sv, 4 + g);                         \
    }

#define LOADP(Xq, Uq, Zq, sI)                                               \
    {                                                                       \
        u32 _o = ((u32)(sI)) << 8;                                          \
        Xq = *(const uint4*)(XcB + _o + xl);                                \
        Uq = *(const uint2*)(UuB + (_o >> 1) + ul);                         \
        Zq = *(const float4*)(E0B + (_o >> 4));                             \
    }

#define ELOAD(Eq, slot)                                                     \
    {                                                                       \
        int _j = (slot);                                                    \
        if (_j > deg - 1) _j = deg - 1;                                     \
        Eq = bf2f(*(const u16*)(epB + (((u32)(rs + _j)) << 5) + el));       \
    }

#define COMP(Xq, Uq, Eq, Zq, act)                                           \
    {                                                                       \
        pf2 X0 = u2f2(Xq.x), X1 = u2f2(Xq.y), X2 = u2f2(Xq.z), X3 = u2f2(Xq.w); \
        float uh[4] = {bflo(Uq.x), bfhi(Uq.x), bflo(Uq.y), bfhi(Uq.y)};     \
        float e0a[4] = {Zq.x, Zq.y, Zq.z, Zq.w};                            \
        _Pragma("unroll") for (int h = 0; h < 4; ++h) {                     \
            pf2 p2 = {Eq * uh[h], 0.f};                                     \
            p2 = pkfma(X0, vr[h][0], p2); p2 = pkfma(X1, vr[h][1], p2);     \
            p2 = pkfma(X2, vr[h][2], p2); p2 = pkfma(X3, vr[h][3], p2);     \
            float p = dpp_red16(p2.x + p2.y);                               \
            float wh = (act) ? e0a[h] * __builtin_amdgcn_exp2f(p) : 0.f;    \
            Ss[h] += wh; aE[h] = fmaf(wh, Eq, aE[h]);                       \
            pf2 w2 = {wh, wh};                                              \
            aX[h][0] = pkfma(w2, X0, aX[h][0]);                             \
            aX[h][1] = pkfma(w2, X1, aX[h][1]);                             \
            aX[h][2] = pkfma(w2, X2, aX[h][2]);                             \
            aX[h][3] = pkfma(w2, X3, aX[h][3]);                             \
        }                                                                   \
    }

    int n = nw;
    if (n >= N) return;
    int rs = row_start[n];
    int re = row_start[n + 1];
    while (true) {
        int deg = re - rs;
        int n2 = n + NW;
        bool more = (n2 < N);
        int rs2 = rs, re2 = re;
        if (more) {  // issue next node's CSR bounds early; land during body
            rs2 = row_start[n2];
            re2 = row_start[n2 + 1];
        }
        const char* VrB = (const char*)V + (((u32)n) << 10);
        pf2 vr[4][4];
#pragma unroll
        for (int h = 0; h < 4; ++h) {
            uint4 v = *(const uint4*)(VrB + h * 256 + xl);
            vr[h][0] = u2f2(v.x); vr[h][1] = u2f2(v.y);
            vr[h][2] = u2f2(v.z); vr[h][3] = u2f2(v.w);
        }
        pf2 aX[4][4] = {};
        float Ss[4] = {0.f, 0.f, 0.f, 0.f};
        float aE[4] = {0.f, 0.f, 0.f, 0.f};

        if (deg > 0) {
            int nst = (deg + 7) >> 3;
            int sA0, sA1, sB0, sB1;
            IDXS(sA0, sA1, 0);
            uint4 xP0, xP1; uint2 uP0, uP1; float4 zP0, zP1; float eP0, eP1;
            LOADP(xP0, uP0, zP0, sA0);
            LOADP(xP1, uP1, zP1, sA1);
            ELOAD(eP0, g);
            ELOAD(eP1, 4 + g);
            if (nst > 1) {
                IDXS(sB0, sB1, 1);
            } else {
                sB0 = sA0; sB1 = sA1;
            }
            for (int s = 0; s < nst; ++s) {
                uint4 xc0 = xP0, xc1 = xP1;
                uint2 uc0 = uP0, uc1 = uP1;
                float ec0 = eP0, ec1 = eP1;
                float4 zc0 = zP0, zc1 = zP1;
                int base = s * 8;
                if (s + 1 < nst) {
                    LOADP(xP0, uP0, zP0, sB0);
                    LOADP(xP1, uP1, zP1, sB1);
                    ELOAD(eP0, base + 8 + g);
                    ELOAD(eP1, base + 12 + g);
                    if (s + 2 < nst) IDXS(sB0, sB1, s + 2);
                }
                COMP(xc0, uc0, ec0, zc0, base + g < deg);
                COMP(xc1, uc1, ec1, zc1, base + 4 + g < deg);
            }
        }
        // cross-group reduce (sum over the 4 edge-groups)
#pragma unroll
        for (int h = 0; h < 4; ++h) {
#pragma unroll
            for (int i = 0; i < 4; ++i) {
                pf2 v = aX[h][i];
                v.x += __shfl_xor(v.x, 16); v.y += __shfl_xor(v.y, 16);
                v.x += __shfl_xor(v.x, 32); v.y += __shfl_xor(v.y, 32);
                aX[h][i] = v;
            }
            Ss[h] += __shfl_xor(Ss[h], 16); Ss[h] += __shfl_xor(Ss[h], 32);
            aE[h] += __shfl_xor(aE[h], 16); aE[h] += __shfl_xor(aE[h], 32);
        }
        // finalize: group g owns head g over the full k range
        pf2 axg[4];
#pragma unroll
        for (int i = 0; i < 4; ++i)
            axg[i] = g == 0 ? aX[0][i] : g == 1 ? aX[1][i] : g == 2 ? aX[2][i] : aX[3][i];
        float aEg = g == 0 ? aE[0] : g == 1 ? aE[1] : g == 2 ? aE[2] : aE[3];
        float Sg = g == 0 ? Ss[0] : g == 1 ? Ss[1] : g == 2 ? Ss[2] : Ss[3];
        const pf2* Wp = (const pf2*)Wl;
#pragma unroll
        for (int kk = 0; kk < 16; ++kk) {
            float a = __shfl(aEg, (g << 4) | kk);  // broadcast within own group
            pf2 a2 = {a, a};
            int base = (kk << 6) + k16;  // same addr across groups -> LDS broadcast
            axg[0] = pkfma(a2, Wp[base], axg[0]);
            axg[1] = pkfma(a2, Wp[base + 16], axg[1]);
            axg[2] = pkfma(a2, Wp[base + 32], axg[2]);
            axg[3] = pkfma(a2, Wp[base + 48], axg[3]);
        }
        {
            float inv = (deg > 0 && Sg > 0.f) ? 1.f / Sg : 0.f;
            float bes = (deg > 0) ? 1.f : 0.f;
            const float* br = &b_edge[8 * k16];
            u32 o0 = (u32)f2bf(axg[0].x * inv + bes * br[0]) |
                     ((u32)f2bf(axg[0].y * inv + bes * br[1]) << 16);
            u32 o1 = (u32)f2bf(axg[1].x * inv + bes * br[2]) |
                     ((u32)f2bf(axg[1].y * inv + bes * br[3]) << 16);
            u32 o2 = (u32)f2bf(axg[2].x * inv + bes * br[4]) |
                     ((u32)f2bf(axg[2].y * inv + bes * br[5]) << 16);
            u32 o3 = (u32)f2bf(axg[3].x * inv + bes * br[6]) |
                     ((u32)f2bf(axg[3].y * inv + bes * br[7]) << 16);
            uint4 st = {o0, o1, o2, o3};
            *(uint4*)((char*)agg + (((u32)n) << 10) + g * 256 + xl) = st;
        }
        if (!more) break;
        n = n2; rs = rs2; re = re2;
    }
#undef IDXS
#undef LOADP
#undef ELOAD
#undef COMP
}

// ---------------- G3 (MFMA): out = relu(x + agg @ W_out + b_out) ---------------------
__global__ __launch_bounds__(256) void g3_kernel(const u16* __restrict__ Xc,
                                                 const u16* __restrict__ agg,
                                                 const u16* __restrict__ WoT,
                                                 const float* __restrict__ bout,
                                                 const int* __restrict__ avgflag,
                                                 float* __restrict__ out, int N) {
    int t = threadIdx.x;
    int r0 = blockIdx.x * 64;
    if (*avgflag) {
        for (int i = t; i < 64 * 128; i += 256) {
            int n = r0 + (i >> 7), j = i & 127;
            if (n < N) {
                float s = 0.f;
#pragma unroll
                for (int h = 0; h < 4; ++h) s += bf2f(agg[(size_t)n * 512 + h * 128 + j]);
                float v = bf2f(Xc[(size_t)n * 128 + j]) + 0.25f * s;
                out[(size_t)n * 128 + j] = v > 0.f ? v : 0.f;
            }
        }
        return;
    }
    __shared__ u16 Asm[64][72];
    __shared__ u16 Bsm[128][72];
    int lane = t & 63, wave = t >> 6;
    int wm = wave >> 1, wn = wave & 1;
    int lr = lane & 15, lk = lane >> 4;
    f4 acc[2][4] = {};
    for (int kb = 0; kb < 8; ++kb) {
        if (kb) __syncthreads();
        {
            int row = t >> 2, ks = (t & 3) * 16;
            int r = r0 + row;
            uint4 v0 = {0, 0, 0, 0}, v1 = {0, 0, 0, 0};
            if (r < N) {
                const u16* src = &agg[(size_t)r * 512 + kb * 64 + ks];
                v0 = *(const uint4*)src;
                v1 = *(const uint4*)(src + 8);
            }
            *(uint4*)&Asm[row][ks] = v0;
            *(uint4*)&Asm[row][ks + 8] = v1;
        }
        {
            int col = t >> 1, ks = (t & 1) * 32;
            const u16* src = &WoT[(size_t)col * 512 + kb * 64 + ks];
            uint4 v0 = *(const uint4*)src;
            uint4 v1 = *(const uint4*)(src + 8);
            uint4 v2 = *(const uint4*)(src + 16);
            uint4 v3 = *(const uint4*)(src + 24);
            *(uint4*)&Bsm[col][ks] = v0;
            *(uint4*)&Bsm[col][ks + 8] = v1;
            *(uint4*)&Bsm[col][ks + 16] = v2;
            *(uint4*)&Bsm[col][ks + 24] = v3;
        }
        __syncthreads();
#pragma unroll
        for (int kk = 0; kk < 2; ++kk) {
            bh8 a[2], b[4];
#pragma unroll
            for (int am = 0; am < 2; ++am)
                a[am] = *(const bh8*)&Asm[wm * 32 + am * 16 + lr][kk * 32 + lk * 8];
#pragma unroll
            for (int bn = 0; bn < 4; ++bn)
                b[bn] = *(const bh8*)&Bsm[wn * 64 + bn * 16 + lr][kk * 32 + lk * 8];
#pragma unroll
            for (int am = 0; am < 2; ++am)
#pragma unroll
                for (int bn = 0; bn < 4; ++bn)
                    acc[am][bn] = __builtin_amdgcn_mfma_f32_16x16x32_bf16(a[am], b[bn], acc[am][bn], 0, 0, 0);
        }
    }
#pragma unroll
    for (int am = 0; am < 2; ++am)
#pragma unroll
        for (int bn = 0; bn < 4; ++bn) {
            int c = wn * 64 + bn * 16 + lr;
            float bc = bout[c];
#pragma unroll
            for (int q = 0; q < 4; ++q) {
                int r = r0 + wm * 32 + am * 16 + lk * 4 + q;
                if (r < N) {
                    float v = acc[am][bn][q] + bc + bf2f(Xc[(size_t)r * 128 + c]);
                    out[(size_t)r * 128 + c] = v > 0.f ? v : 0.f;
                }
            }
        }
}

// ---------------- launch --------------------------------------------------------------
extern "C" void kernel_launch(void* const* d_in, const int* in_sizes, int n_in, void* d_out,
                              int out_size, void* d_ws, size_t ws_size, hipStream_t stream) {
    const float* nodes = (const float*)d_in[0];
    const float* edges = (const float*)d_in[1];
    const int* senders = (const int*)d_in[2];
    const int* receivers = (const int*)d_in[3];
    const int* avgflag = (const int*)d_in[4];
    const float* W_node = (const float*)d_in[5];
    const float* b_node = (const float*)d_in[6];
    const float* W_edge = (const float*)d_in[7];
    const float* b_edge = (const float*)d_in[8];
    const float* Wk_s = (const float*)d_in[9];
    const float* bk_s = (const float*)d_in[10];
    const float* Wk_r = (const float*)d_in[11];
    const float* bk_r = (const float*)d_in[12];
    const float* W_out = (const float*)d_in[13];
    const float* b_out = (const float*)d_in[14];
    int N = in_sizes[0] / 64;
    int E = in_sizes[2];
    float* outp = (float*)d_out;

    char* base = (char*)d_ws;
    size_t off = 0;
    auto alloc = [&](size_t nbytes) -> char* {
        char* p = base + off;
        off = (off + nbytes + 255) & ~(size_t)255;
        return p;
    };
    u16* Xc = (u16*)alloc((size_t)N * 128 * 2);
    u16* V = (u16*)alloc((size_t)N * 512 * 2);
    u16* U = (u16*)alloc((size_t)N * 64 * 2);
    float* E0 = (float*)alloc((size_t)N * 4 * 4);
    u16* agg = (u16*)alloc((size_t)N * 512 * 2);
    int* deg = (int*)alloc((size_t)N * 4);
    int* row_start = (int*)alloc((size_t)(N + 1) * 4);
    int* cursor = (int*)alloc((size_t)N * 4);
    int* s_csr = (int*)alloc((size_t)E * 4);
    u16* eperm = (u16*)alloc((size_t)E * 16 * 2);
    int* pre = (int*)alloc((size_t)N * 4);
    int* bsum = (int*)alloc((size_t)128 * 4);
    int* boff = (int*)alloc((size_t)128 * 4);
    float* A = (float*)alloc((size_t)4 * 64 * 128 * 4);
    float* B = (float*)alloc((size_t)4 * 64 * 128 * 4);
    float* ybr = (float*)alloc((size_t)4 * 128 * 4);
    float* ybs = (float*)alloc((size_t)4 * 128 * 4);
    float* biasrow = (float*)alloc((size_t)712 * 4);
    u16* WfT = (u16*)alloc((size_t)768 * 64 * 2);
    u16* WoT = (u16*)alloc((size_t)128 * 512 * 2);

    int nb = (N + 1023) >> 10;

    hipMemsetAsync(deg, 0, (size_t)N * 4, stream);
    k0a_kernel<<<(132096 + 255) / 256, 256, 0, stream>>>(W_node, Wk_s, Wk_r, W_out, b_node,
                                                         bk_s, bk_r, A, B, WoT, ybs, ybr);
    k0b_kernel<<<(65 * 708 + 60 * 64 + 255) / 256, 256, 0, stream>>>(
        W_node, b_node, A, B, ybr, ybs, Wk_s, W_edge, bk_s, b_edge, WfT, biasrow);
    dim3 g1grid((N + 63) / 64, 6);
    g1_kernel<<<g1grid, 256, 0, stream>>>(nodes, WfT, biasrow, Xc, V, U, E0, N);
    hist_kernel<<<(E + 255) / 256, 256, 0, stream>>>(receivers, deg, E);
    scan1_kernel<<<nb, 1024, 0, stream>>>(deg, pre, bsum, N);
    scan2_kernel<<<1, 64, 0, stream>>>(bsum, boff, nb);
    scan3_kernel<<<(N + 1024) / 1024, 1024, 0, stream>>>(pre, boff, row_start, cursor, N);
    scatter_kernel<<<(E + 255) / 256, 256, 0, stream>>>(receivers, senders, edges, cursor,
                                                        s_csr, eperm, E);
    en_kernel<<<4096, 256, 0, stream>>>(row_start, s_csr, eperm, Xc, V, U, E0, W_edge,
                                        b_edge, agg, N);
    g3_kernel<<<(N + 63) / 64, 256, 0, stream>>>(Xc, agg, WoT, b_out, avgflag, outp, N);
}

// Round 15
// 302.902 us; speedup vs baseline: 1.7255x; 1.0409x over previous
//
#include <hip/hip_runtime.h>

typedef unsigned short u16;
typedef unsigned int u32;
typedef short bh8 __attribute__((ext_vector_type(8)));   // 8 bf16 (A/B frag)
typedef float f4 __attribute__((ext_vector_type(4)));    // 4 f32 (C/D frag)
typedef float pf2 __attribute__((ext_vector_type(2)));   // packed f32 pair

__device__ __forceinline__ float bf2f(u16 h) { return __uint_as_float(((u32)h) << 16); }
__device__ __forceinline__ float bflo(u32 u) { return __uint_as_float(u << 16); }
__device__ __forceinline__ float bfhi(u32 u) { return __uint_as_float(u & 0xffff0000u); }
__device__ __forceinline__ u16 f2bf(float f) {
    u32 x = __float_as_uint(f);
    return (u16)((x + 0x7fffu + ((x >> 16) & 1u)) >> 16);  // RNE
}
__device__ __forceinline__ pf2 pkfma(pf2 a, pf2 b, pf2 c) {
    pf2 d;
    asm("v_pk_fma_f32 %0, %1, %2, %3" : "=v"(d) : "v"(a), "v"(b), "v"(c));
    return d;
}
__device__ __forceinline__ pf2 u2f2(u32 u) {
    pf2 r;
    r.x = bflo(u);
    r.y = bfhi(u);
    return r;
}

#define KSCL 0.12751744336457488f  // (1/sqrt(128)) * log2(e)

// ---------------- K0a: A_h = W_node@Wk_r[h], B_h = W_node@Wk_s[h], WoT, yb vectors ---
// idx < 65536: A/B.  [65536,131072): WoT transpose.  [131072,132096): ybs/ybr.
__global__ void k0a_kernel(const float* __restrict__ Wn, const float* __restrict__ Wks,
                           const float* __restrict__ Wkr, const float* __restrict__ Wout,
                           const float* __restrict__ bn, const float* __restrict__ bks,
                           const float* __restrict__ bkr, float* __restrict__ A,
                           float* __restrict__ B, u16* __restrict__ WoT,
                           float* __restrict__ ybs, float* __restrict__ ybr) {
    int idx = blockIdx.x * 256 + threadIdx.x;
    if (idx < 65536) {
        int which = idx >> 15;
        int rem = idx & 32767;
        int h = rem >> 13;
        int r = rem & 8191;
        int a = r >> 7, dp = r & 127;
        const float* W = which ? Wks : Wkr;
        float acc = 0.f;
        for (int d = 0; d < 128; ++d)
            acc += Wn[a * 128 + d] * W[(h * 128 + d) * 128 + dp];
        (which ? B : A)[(h * 64 + a) * 128 + dp] = acc;
    } else if (idx < 131072) {
        int j = idx - 65536;
        int c = j >> 9, k = j & 511;
        WoT[j] = f2bf(Wout[(size_t)k * 128 + c]);
    } else if (idx < 132096) {
        int j = idx - 131072;
        int which = j >> 9;
        int rem = j & 511;
        int h = rem >> 7, dp = rem & 127;
        const float* W = which ? Wks : Wkr;
        const float* b = which ? bks : bkr;
        float acc = b[h * 128 + dp];
        for (int d = 0; d < 128; ++d) acc += bn[d] * W[(h * 128 + d) * 128 + dp];
        (which ? ybs : ybr)[h * 128 + dp] = acc;
    }
}

// ---------------- K0b: assemble WfT [768 x 64] (bf16, transposed) + biasrow[708] -----
// col c: [0:128) x | [128:640) v(h,i) | [640:704) u k-major | [704:708) c0_h | [708:768)=0
__global__ void k0b_kernel(const float* __restrict__ Wn, const float* __restrict__ bn,
                           const float* __restrict__ A, const float* __restrict__ B,
                           const float* __restrict__ ybr, const float* __restrict__ ybs,
                           const float* __restrict__ Wks, const float* __restrict__ Wedge,
                           const float* __restrict__ bks, const float* __restrict__ bedge,
                           u16* __restrict__ WfT, float* __restrict__ biasrow) {
    int idx = blockIdx.x * 256 + threadIdx.x;  // 65*708 + 60*64 (zero tail)
    if (idx >= 65 * 708 + 60 * 64) return;
    if (idx >= 65 * 708) {
        int j = idx - 65 * 708;
        WfT[(708 + (j >> 6)) * 64 + (j & 63)] = 0;
        return;
    }
    int a = idx / 708, c = idx % 708;
    float val;
    if (c < 128) {
        val = (a < 64) ? Wn[a * 128 + c] : bn[c];
    } else if (c < 640) {
        int h = (c - 128) >> 7, i = (c - 128) & 127;
        const float* rv = (a < 64) ? &A[(h * 64 + a) * 128] : &ybr[h * 128];
        float s = 0.f;
        for (int d = 0; d < 128; ++d) s += rv[d] * Wks[(h * 128 + i) * 128 + d];
        val = s;
    } else if (c < 704) {
        int k = (c - 640) >> 2, h = (c - 640) & 3;
        const float* rv = (a < 64) ? &B[(h * 64 + a) * 128] : &ybs[h * 128];
        float s = 0.f;
        for (int d = 0; d < 128; ++d) s += rv[d] * Wedge[k * 128 + d];
        val = s;
    } else {
        int h = c - 704;
        const float* rv = (a < 64) ? &B[(h * 64 + a) * 128] : &ybs[h * 128];
        float s = 0.f;
        for (int d = 0; d < 128; ++d) s += rv[d] * bedge[d];
        val = s;
    }
    if (a < 64) WfT[(size_t)c * 64 + a] = f2bf(val);
    else biasrow[c] = val;
}

// ---------------- G1 (MFMA): split tables Xc[N,128], V[N,512](pre-scaled), U[N,64],
//                  E0[N,4] = exp2(kscl*c0) ------------------------------------------
__global__ __launch_bounds__(256) void g1_kernel(const float* __restrict__ nodes,
                                                 const u16* __restrict__ WfT,
                                                 const float* __restrict__ biasrow,
                                                 u16* __restrict__ Xc, u16* __restrict__ V,
                                                 u16* __restrict__ U, float* __restrict__ E0,
                                                 int N) {
    __shared__ u16 Asm[64][72];
    __shared__ u16 Bsm[128][72];
    int t = threadIdx.x;
    int r0 = blockIdx.x * 64, c0 = blockIdx.y * 128;
    {
        int row = t >> 2, cb = (t & 3) * 16;
        int r = r0 + row;
        u16 pk[16];
        if (r < N) {
            const float* src = &nodes[(size_t)r * 64 + cb];
#pragma unroll
            for (int q = 0; q < 16; ++q) pk[q] = f2bf(src[q]);
        } else {
#pragma unroll
            for (int q = 0; q < 16; ++q) pk[q] = 0;
        }
        *(uint4*)&Asm[row][cb] = *(const uint4*)&pk[0];
        *(uint4*)&Asm[row][cb + 8] = *(const uint4*)&pk[8];
    }
    {
        int col = t >> 1, ks = (t & 1) * 32;
        const u16* src = &WfT[(size_t)(c0 + col) * 64 + ks];
        uint4 v0 = *(const uint4*)src;
        uint4 v1 = *(const uint4*)(src + 8);
        uint4 v2 = *(const uint4*)(src + 16);
        uint4 v3 = *(const uint4*)(src + 24);
        *(uint4*)&Bsm[col][ks] = v0;
        *(uint4*)&Bsm[col][ks + 8] = v1;
        *(uint4*)&Bsm[col][ks + 16] = v2;
        *(uint4*)&Bsm[col][ks + 24] = v3;
    }
    __syncthreads();
    int lane = t & 63, wave = t >> 6;
    int wm = wave >> 1, wn = wave & 1;
    int lr = lane & 15, lk = lane >> 4;
    f4 acc[2][4] = {};
#pragma unroll
    for (int kk = 0; kk < 2; ++kk) {
        bh8 a[2], b[4];
#pragma unroll
        for (int am = 0; am < 2; ++am)
            a[am] = *(const bh8*)&Asm[wm * 32 + am * 16 + lr][kk * 32 + lk * 8];
#pragma unroll
        for (int bn = 0; bn < 4; ++bn)
            b[bn] = *(const bh8*)&Bsm[wn * 64 + bn * 16 + lr][kk * 32 + lk * 8];
#pragma unroll
        for (int am = 0; am < 2; ++am)
#pragma unroll
            for (int bn = 0; bn < 4; ++bn)
                acc[am][bn] = __builtin_amdgcn_mfma_f32_16x16x32_bf16(a[am], b[bn], acc[am][bn], 0, 0, 0);
    }
#pragma unroll
    for (int am = 0; am < 2; ++am)
#pragma unroll
        for (int bn = 0; bn < 4; ++bn) {
            int c = c0 + wn * 64 + bn * 16 + lr;
            if (c < 708) {
                float brow = biasrow[c];
#pragma unroll
                for (int q = 0; q < 4; ++q) {
                    int r = r0 + wm * 32 + am * 16 + lk * 4 + q;
                    if (r < N) {
                        float val = acc[am][bn][q] + brow;
                        if (c < 128) Xc[(size_t)r * 128 + c] = f2bf(val);
                        else if (c < 640) V[(size_t)r * 512 + (c - 128)] = f2bf(val * KSCL);
                        else if (c < 704) U[(size_t)r * 64 + (c - 640)] = f2bf(val * KSCL);
                        else E0[(size_t)r * 4 + (c - 704)] = __builtin_amdgcn_exp2f(val * KSCL);
                    }
                }
            }
        }
}

// ---------------- CSR build ----------------------------------------------------------
__global__ void hist_kernel(const int* __restrict__ recv, int* __restrict__ deg, int E) {
    int e = blockIdx.x * 256 + threadIdx.x;
    if (e < E) atomicAdd(&deg[recv[e]], 1);
}

__global__ __launch_bounds__(1024) void scan1_kernel(const int* __restrict__ deg,
                                                     int* __restrict__ pre,
                                                     int* __restrict__ bsum, int N) {
    __shared__ int sm[1024];
    int b = blockIdx.x, t = threadIdx.x;
    int i = b * 1024 + t;
    int v = (i < N) ? deg[i] : 0;
    sm[t] = v;
    __syncthreads();
    for (int off = 1; off < 1024; off <<= 1) {
        int u = (t >= off) ? sm[t - off] : 0;
        __syncthreads();
        sm[t] += u;
        __syncthreads();
    }
    if (i < N) pre[i] = sm[t] - v;
    if (t == 1023) bsum[b] = sm[1023];
}

__global__ void scan2_kernel(int* __restrict__ bsum, int* __restrict__ boff, int nb) {
    int t = threadIdx.x;  // 64 threads, nb <= 64
    int own = (t < nb) ? bsum[t] : 0;
    int v = own;
#pragma unroll
    for (int off = 1; off < 64; off <<= 1) {
        int u = __shfl_up(v, off);
        if (t >= off) v += u;
    }
    if (t < nb) boff[t] = v - own;
    if (t == 63) boff[64] = v;
}

__global__ void scan3_kernel(const int* __restrict__ pre, const int* __restrict__ boff,
                             int* __restrict__ row_start, int* __restrict__ cursor, int N) {
    int i = blockIdx.x * 1024 + threadIdx.x;
    if (i < N) {
        int rsv = pre[i] + boff[i >> 10];
        row_start[i] = rsv;
        cursor[i] = rsv;
    }
    if (i == N) row_start[N] = boff[64];
}

// scatter: s_csr[p] = sender; eperm[p][16] = bf16 edge features in CSR order
__global__ void scatter_kernel(const int* __restrict__ recv, const int* __restrict__ senders,
                               const float* __restrict__ edges, int* __restrict__ cursor,
                               int* __restrict__ s_csr, u16* __restrict__ eperm, int E) {
    int e = blockIdx.x * 256 + threadIdx.x;
    if (e < E) {
        int s = senders[e];
        const float* src = &edges[(size_t)e * 16];
        u16 tmp[16];
#pragma unroll
        for (int k = 0; k < 16; ++k) tmp[k] = f2bf(src[k]);
        int p = atomicAdd(&cursor[recv[e]], 1);
        s_csr[p] = s;
        u16* dst = &eperm[(size_t)p * 16];
        *(uint4*)dst = *(const uint4*)&tmp[0];
        *(uint4*)(dst + 8) = *(const uint4*)&tmp[8];
    }
}

// ---------------- EN v12b: fused v_add_f32_dpp reduces + literal ds_swizzle bcast ----
// Wave = node. Lane = (g,k16). Group g handles edge slot 8s+g and 8s+4+g; k16 = 8 ch.
__global__ __launch_bounds__(256, 3) void en_kernel(const int* __restrict__ row_start,
                                                    const int* __restrict__ s_csr,
                                                    const u16* __restrict__ eperm,
                                                    const u16* __restrict__ Xc,
                                                    const u16* __restrict__ V,
                                                    const u16* __restrict__ Uu,
                                                    const float* __restrict__ E0,
                                                    const float* __restrict__ W_edge,
                                                    const float* __restrict__ b_edge,
                                                    u16* __restrict__ agg, int N) {
    __shared__ float Wl[2048];  // swizzled: (k, ch=8*k16+2i+b) at k*128+32*i+2*k16+b
    int t = threadIdx.x;
    for (int i = t; i < 2048; i += 256) {
        int k = i >> 7, ch = i & 127;
        int pos = (k << 7) | ((((ch >> 1) & 3) << 5) | (((ch >> 3) & 15) << 1) | (ch & 1));
        Wl[pos] = W_edge[i];
    }
    __syncthreads();
    int lane = t & 63, wid = t >> 6;
    int g = lane >> 4, k16 = lane & 15;
    int nw = blockIdx.x * 4 + wid;
    int NW = gridDim.x * 4;

    const char* XcB = (const char*)Xc;
    const char* UuB = (const char*)Uu;
    const char* E0B = (const char*)E0;
    const char* epB = (const char*)eperm;
    const char* scB = (const char*)s_csr;
    const u32 xl = (u32)k16 << 4;  // lane offsets
    const u32 ul = (u32)k16 << 3;
    const u32 el = (u32)k16 << 1;

#define IDXS(sa, sb, s_)                                                    \
    {                                                                       \
        int sv = 0;                                                         \
        if (lane < 8) {                                                     \
            int jj = (s_)*8 + lane;                                         \
            if (jj >= deg) jj = deg - 1;                                    \
            sv = *(const int*)(scB + (((u32)(rs + jj)) << 2));              \
        }                                                                   \
        sa = __shfl(sv, g); sb = __shfl(sv, 4 + g);                         \
    }

#define LOADP(Xq, Uq, Zq, sI)                                               \
    {                                                                       \
        u32 _o = ((u32)(sI)) << 8;                                          \
        Xq = *(const uint4*)(XcB + _o + xl);                                \
        Uq = *(const uint2*)(UuB + (_o >> 1) + ul);                         \
        Zq = *(const float4*)(E0B + (_o >> 4));                             \
    }

#define ELOAD(Eq, slot)                                                     \
    {                                                                       \
        int _j = (slot);                                                    \
        if (_j > deg - 1) _j = deg - 1;                                     \
        Eq = bf2f(*(const u16*)(epB + (((u32)(rs + _j)) << 5) + el));       \
    }

// 4 independent 16-lane butterfly sums, one fused dpp-add per stage per value.
// Chains interleaved (distance 4 >= 2-cycle DPP hazard); s_nop 1 guards the
// unknown distance to the compiler-scheduled producers of pr0..pr3.
#define DPPRED4(pr0, pr1, pr2, pr3)                                         \
    asm("s_nop 1\n\t"                                                       \
        "v_add_f32_dpp %0, %0, %0 quad_perm:[1,0,3,2] row_mask:0xf bank_mask:0xf\n\t" \
        "v_add_f32_dpp %1, %1, %1 quad_perm:[1,0,3,2] row_mask:0xf bank_mask:0xf\n\t" \
        "v_add_f32_dpp %2, %2, %2 quad_perm:[1,0,3,2] row_mask:0xf bank_mask:0xf\n\t" \
        "v_add_f32_dpp %3, %3, %3 quad_perm:[1,0,3,2] row_mask:0xf bank_mask:0xf\n\t" \
        "v_add_f32_dpp %0, %0, %0 quad_perm:[2,3,0,1] row_mask:0xf bank_mask:0xf\n\t" \
        "v_add_f32_dpp %1, %1, %1 quad_perm:[2,3,0,1] row_mask:0xf bank_mask:0xf\n\t" \
        "v_add_f32_dpp %2, %2, %2 quad_perm:[2,3,0,1] row_mask:0xf bank_mask:0xf\n\t" \
        "v_add_f32_dpp %3, %3, %3 quad_perm:[2,3,0,1] row_mask:0xf bank_mask:0xf\n\t" \
        "v_add_f32_dpp %0, %0, %0 row_half_mirror row_mask:0xf bank_mask:0xf\n\t" \
        "v_add_f32_dpp %1, %1, %1 row_half_mirror row_mask:0xf bank_mask:0xf\n\t" \
        "v_add_f32_dpp %2, %2, %2 row_half_mirror row_mask:0xf bank_mask:0xf\n\t" \
        "v_add_f32_dpp %3, %3, %3 row_half_mirror row_mask:0xf bank_mask:0xf\n\t" \
        "v_add_f32_dpp %0, %0, %0 row_mirror row_mask:0xf bank_mask:0xf\n\t" \
        "v_add_f32_dpp %1, %1, %1 row_mirror row_mask:0xf bank_mask:0xf\n\t" \
        "v_add_f32_dpp %2, %2, %2 row_mirror row_mask:0xf bank_mask:0xf\n\t" \
        "v_add_f32_dpp %3, %3, %3 row_mirror row_mask:0xf bank_mask:0xf"    \
        : "+v"(pr0), "+v"(pr1), "+v"(pr2), "+v"(pr3))

#define COMP(Xq, Uq, Eq, Zq, act)                                           \
    {                                                                       \
        pf2 X0 = u2f2(Xq.x), X1 = u2f2(Xq.y), X2 = u2f2(Xq.z), X3 = u2f2(Xq.w); \
        float uh[4] = {bflo(Uq.x), bfhi(Uq.x), bflo(Uq.y), bfhi(Uq.y)};     \
        float e0a[4] = {Zq.x, Zq.y, Zq.z, Zq.w};                            \
        float pr[4];                                                        \
        _Pragma("unroll") for (int h = 0; h < 4; ++h) {                     \
            pf2 p2 = {Eq * uh[h], 0.f};                                     \
            p2 = pkfma(X0, vr[h][0], p2); p2 = pkfma(X1, vr[h][1], p2);     \
            p2 = pkfma(X2, vr[h][2], p2); p2 = pkfma(X3, vr[h][3], p2);     \
            pr[h] = p2.x + p2.y;                                            \
        }                                                                   \
        DPPRED4(pr[0], pr[1], pr[2], pr[3]);                                \
        _Pragma("unroll") for (int h = 0; h < 4; ++h) {                     \
            float wh = (act) ? e0a[h] * __builtin_amdgcn_exp2f(pr[h]) : 0.f; \
            Ss[h] += wh; aE[h] = fmaf(wh, Eq, aE[h]);                       \
            pf2 w2 = {wh, wh};                                              \
            aX[h][0] = pkfma(w2, X0, aX[h][0]);                             \
            aX[h][1] = pkfma(w2, X1, aX[h][1]);                             \
            aX[h][2] = pkfma(w2, X2, aX[h][2]);                             \
            aX[h][3] = pkfma(w2, X3, aX[h][3]);                             \
        }                                                                   \
    }

    int n = nw;
    if (n >= N) return;
    int rs = row_start[n];
    int re = row_start[n + 1];
    while (true) {
        int deg = re - rs;
        int n2 = n + NW;
        bool more = (n2 < N);
        int rs2 = rs, re2 = re;
        if (more) {  // issue next node's CSR bounds early; land during body
            rs2 = row_start[n2];
            re2 = row_start[n2 + 1];
        }
        const char* VrB = (const char*)V + (((u32)n) << 10);
        pf2 vr[4][4];
#pragma unroll
        for (int h = 0; h < 4; ++h) {
            uint4 v = *(const uint4*)(VrB + h * 256 + xl);
            vr[h][0] = u2f2(v.x); vr[h][1] = u2f2(v.y);
            vr[h][2] = u2f2(v.z); vr[h][3] = u2f2(v.w);
        }
        pf2 aX[4][4] = {};
        float Ss[4] = {0.f, 0.f, 0.f, 0.f};
        float aE[4] = {0.f, 0.f, 0.f, 0.f};

        if (deg > 0) {
            int nst = (deg + 7) >> 3;
            int sA0, sA1, sB0, sB1;
            IDXS(sA0, sA1, 0);
            uint4 xP0, xP1; uint2 uP0, uP1; float4 zP0, zP1; float eP0, eP1;
            LOADP(xP0, uP0, zP0, sA0);
            LOADP(xP1, uP1, zP1, sA1);
            ELOAD(eP0, g);
            ELOAD(eP1, 4 + g);
            if (nst > 1) {
                IDXS(sB0, sB1, 1);
            } else {
                sB0 = sA0; sB1 = sA1;
            }
            for (int s = 0; s < nst; ++s) {
                uint4 xc0 = xP0, xc1 = xP1;
                uint2 uc0 = uP0, uc1 = uP1;
                float ec0 = eP0, ec1 = eP1;
                float4 zc0 = zP0, zc1 = zP1;
                int base = s * 8;
                if (s + 1 < nst) {
                    LOADP(xP0, uP0, zP0, sB0);
                    LOADP(xP1, uP1, zP1, sB1);
                    ELOAD(eP0, base + 8 + g);
                    ELOAD(eP1, base + 12 + g);
                    if (s + 2 < nst) IDXS(sB0, sB1, s + 2);
                }
                COMP(xc0, uc0, ec0, zc0, base + g < deg);
                COMP(xc1, uc1, ec1, zc1, base + 4 + g < deg);
            }
        }
        // cross-group reduce (sum over the 4 edge-groups)
#pragma unroll
        for (int h = 0; h < 4; ++h) {
#pragma unroll
            for (int i = 0; i < 4; ++i) {
                pf2 v = aX[h][i];
                v.x += __shfl_xor(v.x, 16); v.y += __shfl_xor(v.y, 16);
                v.x += __shfl_xor(v.x, 32); v.y += __shfl_xor(v.y, 32);
                aX[h][i] = v;
            }
            Ss[h] += __shfl_xor(Ss[h], 16); Ss[h] += __shfl_xor(Ss[h], 32);
            aE[h] += __shfl_xor(aE[h], 16); aE[h] += __shfl_xor(aE[h], 32);
        }
        // finalize: group g owns head g over the full k range
        pf2 axg[4];
#pragma unroll
        for (int i = 0; i < 4; ++i)
            axg[i] = g == 0 ? aX[0][i] : g == 1 ? aX[1][i] : g == 2 ? aX[2][i] : aX[3][i];
        float aEg = g == 0 ? aE[0] : g == 1 ? aE[1] : g == 2 ? aE[2] : aE[3];
        float Sg = g == 0 ? Ss[0] : g == 1 ? Ss[1] : g == 2 ? Ss[2] : Ss[3];
        const pf2* Wp = (const pf2*)Wl;
        // broadcast aEg from lane ((lane&0x10)|KK): BitMode swizzle
        // offset = (xor=0)<<10 | (or=KK)<<5 | (and=0x10). Literal per step.
#define FINSTEP(KK)                                                         \
        {                                                                   \
            float a = __int_as_float(__builtin_amdgcn_ds_swizzle(           \
                __float_as_int(aEg), ((KK) << 5) | 0x10));                  \
            pf2 a2 = {a, a};                                                \
            int base = ((KK) << 6) + k16;                                   \
            axg[0] = pkfma(a2, Wp[base], axg[0]);                           \
            axg[1] = pkfma(a2, Wp[base + 16], axg[1]);                      \
            axg[2] = pkfma(a2, Wp[base + 32], axg[2]);                      \
            axg[3] = pkfma(a2, Wp[base + 48], axg[3]);                      \
        }
        FINSTEP(0) FINSTEP(1) FINSTEP(2) FINSTEP(3)
        FINSTEP(4) FINSTEP(5) FINSTEP(6) FINSTEP(7)
        FINSTEP(8) FINSTEP(9) FINSTEP(10) FINSTEP(11)
        FINSTEP(12) FINSTEP(13) FINSTEP(14) FINSTEP(15)
#undef FINSTEP
        {
            float inv = (deg > 0 && Sg > 0.f) ? 1.f / Sg : 0.f;
            float bes = (deg > 0) ? 1.f : 0.f;
            const float* br = &b_edge[8 * k16];
            u32 o0 = (u32)f2bf(axg[0].x * inv + bes * br[0]) |
                     ((u32)f2bf(axg[0].y * inv + bes * br[1]) << 16);
            u32 o1 = (u32)f2bf(axg[1].x * inv + bes * br[2]) |
                     ((u32)f2bf(axg[1].y * inv + bes * br[3]) << 16);
            u32 o2 = (u32)f2bf(axg[2].x * inv + bes * br[4]) |
                     ((u32)f2bf(axg[2].y * inv + bes * br[5]) << 16);
            u32 o3 = (u32)f2bf(axg[3].x * inv + bes * br[6]) |
                     ((u32)f2bf(axg[3].y * inv + bes * br[7]) << 16);
            uint4 st = {o0, o1, o2, o3};
            *(uint4*)((char*)agg + (((u32)n) << 10) + g * 256 + xl) = st;
        }
        if (!more) break;
        n = n2; rs = rs2; re = re2;
    }
#undef IDXS
#undef LOADP
#undef ELOAD
#undef COMP
#undef DPPRED4
}

// ---------------- G3 (MFMA): out = relu(x + agg @ W_out + b_out) ---------------------
__global__ __launch_bounds__(256) void g3_kernel(const u16* __restrict__ Xc,
                                                 const u16* __restrict__ agg,
                                                 const u16* __restrict__ WoT,
                                                 const float* __restrict__ bout,
                                                 const int* __restrict__ avgflag,
                                                 float* __restrict__ out, int N) {
    int t = threadIdx.x;
    int r0 = blockIdx.x * 64;
    if (*avgflag) {
        for (int i = t; i < 64 * 128; i += 256) {
            int n = r0 + (i >> 7), j = i & 127;
            if (n < N) {
                float s = 0.f;
#pragma unroll
                for (int h = 0; h < 4; ++h) s += bf2f(agg[(size_t)n * 512 + h * 128 + j]);
                float v = bf2f(Xc[(size_t)n * 128 + j]) + 0.25f * s;
                out[(size_t)n * 128 + j] = v > 0.f ? v : 0.f;
            }
        }
        return;
    }
    __shared__ u16 Asm[64][72];
    __shared__ u16 Bsm[128][72];
    int lane = t & 63, wave = t >> 6;
    int wm = wave >> 1, wn = wave & 1;
    int lr = lane & 15, lk = lane >> 4;
    f4 acc[2][4] = {};
    for (int kb = 0; kb < 8; ++kb) {
        if (kb) __syncthreads();
        {
            int row = t >> 2, ks = (t & 3) * 16;
            int r = r0 + row;
            uint4 v0 = {0, 0, 0, 0}, v1 = {0, 0, 0, 0};
            if (r < N) {
                const u16* src = &agg[(size_t)r * 512 + kb * 64 + ks];
                v0 = *(const uint4*)src;
                v1 = *(const uint4*)(src + 8);
            }
            *(uint4*)&Asm[row][ks] = v0;
            *(uint4*)&Asm[row][ks + 8] = v1;
        }
        {
            int col = t >> 1, ks = (t & 1) * 32;
            const u16* src = &WoT[(size_t)col * 512 + kb * 64 + ks];
            uint4 v0 = *(const uint4*)src;
            uint4 v1 = *(const uint4*)(src + 8);
            uint4 v2 = *(const uint4*)(src + 16);
            uint4 v3 = *(const uint4*)(src + 24);
            *(uint4*)&Bsm[col][ks] = v0;
            *(uint4*)&Bsm[col][ks + 8] = v1;
            *(uint4*)&Bsm[col][ks + 16] = v2;
            *(uint4*)&Bsm[col][ks + 24] = v3;
        }
        __syncthreads();
#pragma unroll
        for (int kk = 0; kk < 2; ++kk) {
            bh8 a[2], b[4];
#pragma unroll
            for (int am = 0; am < 2; ++am)
                a[am] = *(const bh8*)&Asm[wm * 32 + am * 16 + lr][kk * 32 + lk * 8];
#pragma unroll
            for (int bn = 0; bn < 4; ++bn)
                b[bn] = *(const bh8*)&Bsm[wn * 64 + bn * 16 + lr][kk * 32 + lk * 8];
#pragma unroll
            for (int am = 0; am < 2; ++am)
#pragma unroll
                for (int bn = 0; bn < 4; ++bn)
                    acc[am][bn] = __builtin_amdgcn_mfma_f32_16x16x32_bf16(a[am], b[bn], acc[am][bn], 0, 0, 0);
        }
    }
#pragma unroll
    for (int am = 0; am < 2; ++am)
#pragma unroll
        for (int bn = 0; bn < 4; ++bn) {
            int c = wn * 64 + bn * 16 + lr;
            float bc = bout[c];
#pragma unroll
            for (int q = 0; q < 4; ++q) {
                int r = r0 + wm * 32 + am * 16 + lk * 4 + q;
                if (r < N) {
                    float v = acc[am][bn][q] + bc + bf2f(Xc[(size_t)r * 128 + c]);
                    out[(size_t)r * 128 + c] = v > 0.f ? v : 0.f;
                }
            }
        }
}

// ---------------- launch --------------------------------------------------------------
extern "C" void kernel_launch(void* const* d_in, const int* in_sizes, int n_in, void* d_out,
                              int out_size, void* d_ws, size_t ws_size, hipStream_t stream) {
    const float* nodes = (const float*)d_in[0];
    const float* edges = (const float*)d_in[1];
    const int* senders = (const int*)d_in[2];
    const int* receivers = (const int*)d_in[3];
    const int* avgflag = (const int*)d_in[4];
    const float* W_node = (const float*)d_in[5];
    const float* b_node = (const float*)d_in[6];
    const float* W_edge = (const float*)d_in[7];
    const float* b_edge = (const float*)d_in[8];
    const float* Wk_s = (const float*)d_in[9];
    const float* bk_s = (const float*)d_in[10];
    const float* Wk_r = (const float*)d_in[11];
    const float* bk_r = (const float*)d_in[12];
    const float* W_out = (const float*)d_in[13];
    const float* b_out = (const float*)d_in[14];
    int N = in_sizes[0] / 64;
    int E = in_sizes[2];
    float* outp = (float*)d_out;

    char* base = (char*)d_ws;
    size_t off = 0;
    auto alloc = [&](size_t nbytes) -> char* {
        char* p = base + off;
        off = (off + nbytes + 255) & ~(size_t)255;
        return p;
    };
    u16* Xc = (u16*)alloc((size_t)N * 128 * 2);
    u16* V = (u16*)alloc((size_t)N * 512 * 2);
    u16* U = (u16*)alloc((size_t)N * 64 * 2);
    float* E0 = (float*)alloc((size_t)N * 4 * 4);
    u16* agg = (u16*)alloc((size_t)N * 512 * 2);
    int* deg = (int*)alloc((size_t)N * 4);
    int* row_start = (int*)alloc((size_t)(N + 1) * 4);
    int* cursor = (int*)alloc((size_t)N * 4);
    int* s_csr = (int*)alloc((size_t)E * 4);
    u16* eperm = (u16*)alloc((size_t)E * 16 * 2);
    int* pre = (int*)alloc((size_t)N * 4);
    int* bsum = (int*)alloc((size_t)128 * 4);
    int* boff = (int*)alloc((size_t)128 * 4);
    float* A = (float*)alloc((size_t)4 * 64 * 128 * 4);
    float* B = (float*)alloc((size_t)4 * 64 * 128 * 4);
    float* ybr = (float*)alloc((size_t)4 * 128 * 4);
    float* ybs = (float*)alloc((size_t)4 * 128 * 4);
    float* biasrow = (float*)alloc((size_t)712 * 4);
    u16* WfT = (u16*)alloc((size_t)768 * 64 * 2);
    u16* WoT = (u16*)alloc((size_t)128 * 512 * 2);

    int nb = (N + 1023) >> 10;

    hipMemsetAsync(deg, 0, (size_t)N * 4, stream);
    k0a_kernel<<<(132096 + 255) / 256, 256, 0, stream>>>(W_node, Wk_s, Wk_r, W_out, b_node,
                                                         bk_s, bk_r, A, B, WoT, ybs, ybr);
    k0b_kernel<<<(65 * 708 + 60 * 64 + 255) / 256, 256, 0, stream>>>(
        W_node, b_node, A, B, ybr, ybs, Wk_s, W_edge, bk_s, b_edge, WfT, biasrow);
    dim3 g1grid((N + 63) / 64, 6);
    g1_kernel<<<g1grid, 256, 0, stream>>>(nodes, WfT, biasrow, Xc, V, U, E0, N);
    hist_kernel<<<(E + 255) / 256, 256, 0, stream>>>(receivers, deg, E);
    scan1_kernel<<<nb, 1024, 0, stream>>>(deg, pre, bsum, N);
    scan2_kernel<<<1, 64, 0, stream>>>(bsum, boff, nb);
    scan3_kernel<<<(N + 1024) / 1024, 1024, 0, stream>>>(pre, boff, row_start, cursor, N);
    scatter_kernel<<<(E + 255) / 256, 256, 0, stream>>>(receivers, senders, edges, cursor,
                                                        s_csr, eperm, E);
    en_kernel<<<4096, 256, 0, stream>>>(row_start, s_csr, eperm, Xc, V, U, E0, W_edge,
                                        b_edge, agg, N);
    g3_kernel<<<(N + 63) / 64, 256, 0, stream>>>(Xc, agg, WoT, b_out, avgflag, outp, N);
}